// Round 5
// baseline (1377.696 us; speedup 1.0000x reference)
//
#include <hip/hip_runtime.h>
#include <math.h>

#define RAD 15
#define DIAM 31

typedef unsigned char u8;

// ---------------- gray + quantize (fp32, exact ref op order) ----------------
__global__ __launch_bounds__(256) void k_gray(const float* __restrict__ img, u8* __restrict__ q){
  int i = blockIdx.x*256 + threadIdx.x;            // 8*256*256 = 524288
  int b = i >> 16, p = i & 65535;
  const float* pb = img + (((size_t)b*3) << 16);
  float r = pb[p], g = pb[65536 + p], bl = pb[131072 + p];
  float gray = __fadd_rn(__fadd_rn(__fmul_rn(0.299f, r), __fmul_rn(0.587f, g)), __fmul_rn(0.116f, bl));
  float t = floorf(__fmul_rn(gray, 255.0f));
  t = fminf(fmaxf(t, 0.0f), 255.0f);
  q[i] = (u8)(int)t;
}

// ---------------- bilateral: fp32 accumulation in exact ref scan order ----------------
__global__ __launch_bounds__(256) void k_bilateral(const u8* __restrict__ q, u8* __restrict__ filt){
  __shared__ int tile[62][62];
  __shared__ float swt[DIAM*DIAM];
  __shared__ float wc[256];
  int b = blockIdx.z;
  int gx0 = blockIdx.x * 32, gy0 = blockIdx.y * 32;
  int tid = threadIdx.x;
  const float inv2sc2 = (float)(-0.5/5625.0);
  const u8* qb = q + ((size_t)b << 16);
  for (int i = tid; i < DIAM*DIAM; i += 256){
    int dx = i / DIAM - RAD, dy = i % DIAM - RAD;
    int r2 = dx*dx + dy*dy;
    swt[i] = (r2 <= RAD*RAD) ? (float)exp(-0.5 * (double)r2 / 225.0) : 0.0f;  // f32(np.exp(f64))
  }
  if (tid < 256){
    float df = (float)tid;
    float t = __fmul_rn(__fmul_rn(inv2sc2, df), df);  // fl32((inv2sc2*d)*d)
    wc[tid] = (float)exp((double)t);                  // correctly-rounded f32 exp
  }
  for (int i = tid; i < 62*62; i += 256){
    int ly = i / 62, lx = i % 62;
    int gy = gy0 + ly - RAD, gx = gx0 + lx - RAD;
    gy = gy < 0 ? -gy : (gy > 255 ? 510 - gy : gy);   // jnp.pad reflect
    gx = gx < 0 ? -gx : (gx > 255 ? 510 - gx : gx);
    tile[ly][lx] = (int)qb[(gy << 8) + gx];
  }
  __syncthreads();
  int tx = tid & 31, ty0 = tid >> 5;                  // 32 cols x 8 rows, 4 px/thread
  int c[4]; float num[4], den[4];
  #pragma unroll
  for (int k = 0; k < 4; ++k){
    c[k] = tile[ty0 + 8*k + RAD][tx + RAD];
    num[k] = 0.f; den[k] = 0.f;
  }
  for (int dx = -RAD; dx <= RAD; ++dx){
    for (int dy = -RAD; dy <= RAD; ++dy){
      int r2 = dx*dx + dy*dy;
      if (r2 > RAD*RAD) continue;
      float sw = swt[(dx+RAD)*DIAM + (dy+RAD)];
      #pragma unroll
      for (int k = 0; k < 4; ++k){
        int sh = tile[ty0 + 8*k + dx + RAD][tx + dy + RAD];
        int d = sh - c[k]; d = d < 0 ? -d : d;
        float w = __fmul_rn(sw, wc[d]);
        num[k] = __fadd_rn(num[k], __fmul_rn(w, (float)sh));
        den[k] = __fadd_rn(den[k], w);
      }
    }
  }
  #pragma unroll
  for (int k = 0; k < 4; ++k){
    int gy = gy0 + ty0 + 8*k, gx = gx0 + tx;
    filt[((size_t)b << 16) + (gy << 8) + gx] = (u8)(int)rintf(__fdiv_rn(num[k], den[k]));
  }
}

// ---------------- LBP code (exact integer compares), u8 ----------------
__global__ __launch_bounds__(256) void k_lbp(const u8* __restrict__ filt, u8* __restrict__ lbp){
  int i = blockIdx.x*256 + threadIdx.x;
  int b = i >> 16, p = i & 65535, y = p >> 8, x = p & 255;
  int v = 0;
  if (y > 0 && y < 255 && x > 0 && x < 255){
    const u8* f = filt + ((size_t)b << 16);
    int c = f[(y << 8) + x];
    int pat = 128;                                    // p7 (0,0): always true
    pat += (f[((y+1) << 8) + x]     >= c) ? 1  : 0;   // p0 (1,0)
    pat += (f[(y << 8) + x - 1]     >= c) ? 6  : 0;   // p1+p2 (0,-1)
    pat += (f[((y-1) << 8) + x - 1] >= c) ? 8  : 0;   // p3 (-1,-1)
    pat += (f[((y-1) << 8) + x]     >= c) ? 48 : 0;   // p4+p5 (-1,0)
    pat += (f[(y << 8) + x + 1]     >= c) ? 64 : 0;   // p6 (0,1)
    v = pat;
  }
  lbp[i] = (u8)v;
}

// ---------------- deterministic per-block channel stats ----------------
template<int OC>
__device__ __forceinline__ void block_stats(const float* acc, float* red, int tid, float* out){
  #pragma unroll
  for (int c0 = 0; c0 < OC; c0 += 8){
    #pragma unroll
    for (int pass = 0; pass < 2; ++pass){
      __syncthreads();
      #pragma unroll
      for (int j = 0; j < 8; ++j){
        float v = acc[c0 + j];
        red[tid*8 + j] = pass ? __fmul_rn(v, v) : v;
      }
      __syncthreads();
      int i = tid >> 5, s = tid & 31;
      float v = 0.f;
      #pragma unroll
      for (int k = 0; k < 8; ++k) v += red[(s + 32*k)*8 + i];
      v += __shfl_xor(v, 1); v += __shfl_xor(v, 2); v += __shfl_xor(v, 4);
      v += __shfl_xor(v, 8); v += __shfl_xor(v, 16);
      if (s == 0) out[2*(c0 + i) + pass] = v;
    }
  }
}

// ---------------- pass A: conv1 stats only (no y1 store) ----------------
__global__ __launch_bounds__(256) void k_stats1(const u8* __restrict__ lbp, const float* __restrict__ w1,
                                                float* __restrict__ part1){
  __shared__ float t[18][18];
  __shared__ float wl[288];
  __shared__ float red[2048];
  int b = blockIdx.z;
  int ty0 = blockIdx.y * 16, tx0 = blockIdx.x * 16;
  int tid = threadIdx.x, tx = tid & 15, ty = tid >> 4;
  for (int i = tid; i < 288; i += 256) wl[i] = w1[i];   // FIX: 288 > 256, strided load
  for (int i = tid; i < 324; i += 256){
    int iy = i / 18, ix = i % 18;
    int gy = ty0 + iy - 1, gx = tx0 + ix - 1;
    float v = 0.f;
    if ((unsigned)gy < 256u && (unsigned)gx < 256u)
      v = __fdiv_rn((float)lbp[((size_t)b << 16) + (gy << 8) + gx], 255.0f);
    t[iy][ix] = v;
  }
  __syncthreads();
  float v[9];
  #pragma unroll
  for (int j = 0; j < 9; ++j) v[j] = t[ty + j/3][tx + j%3];
  float acc[32];
  #pragma unroll
  for (int oc = 0; oc < 32; ++oc){
    float a = 0.f;
    #pragma unroll
    for (int j = 0; j < 9; ++j) a = fmaf(v[j], wl[oc*9 + j], a);
    acc[oc] = a;
  }
  int blk = (blockIdx.z * 16 + blockIdx.y) * 16 + blockIdx.x;
  block_stats<32>(acc, red, tid, part1 + (size_t)blk * 64);
}

// ---------------- finalize BN stats: scale/shift ----------------
__global__ __launch_bounds__(256) void k_stats(const float* __restrict__ part, int stride, int OC,
                                               const float* __restrict__ g, const float* __restrict__ beta,
                                               float* __restrict__ st){
  int ch = blockIdx.x, tid = threadIdx.x;
  double s = 0.0, s2 = 0.0;
  for (int k = tid; k < 2048; k += 256){
    const float* pp = part + (size_t)k * stride + 2*ch;
    s += (double)pp[0]; s2 += (double)pp[1];
  }
  #pragma unroll
  for (int m = 1; m <= 32; m <<= 1){ s += __shfl_xor(s, m); s2 += __shfl_xor(s2, m); }
  __shared__ double red[8];
  if ((tid & 63) == 0){ red[(tid >> 6)*2] = s; red[(tid >> 6)*2 + 1] = s2; }
  __syncthreads();
  if (tid == 0){
    s  = red[0] + red[2] + red[4] + red[6];
    s2 = red[1] + red[3] + red[5] + red[7];
    double mean = s / 524288.0;
    double var  = s2 / 524288.0 - mean*mean;
    double rs   = 1.0 / sqrt(var + 1e-5);
    double sc   = (double)g[ch] * rs;
    st[ch]      = (float)sc;
    st[OC + ch] = (float)((double)beta[ch] - mean * sc);
  }
}

// ---------------- transpose w2 -> [ic*9+tap][oc] ----------------
__global__ __launch_bounds__(256) void k_w2t(const float* __restrict__ w2, float* __restrict__ w2t){
  int i = blockIdx.x*256 + threadIdx.x;
  if (i < 18432){
    int oc = i / 288, r = i % 288;
    w2t[(size_t)r*64 + oc] = w2[i];
  }
}

// ---------------- fused conv1+bn1+relu+conv2 ----------------
// MODE 0: partial stats2; MODE 1: bn2+relu+2x2 maxpool -> out
template<int MODE>
__global__ __launch_bounds__(256) void k_fused(const u8* __restrict__ lbp, const float* __restrict__ w1,
                                               const float* __restrict__ w2t,
                                               const float* __restrict__ st1, const float* __restrict__ st2,
                                               float* __restrict__ part2, float* __restrict__ out){
  __shared__ float lt[20][20];
  __shared__ float wl[288];
  __shared__ float y1h[32][18][18];
  __shared__ float red[2048];
  int b = blockIdx.z;
  int ty0 = blockIdx.y * 16, tx0 = blockIdx.x * 16;
  int tid = threadIdx.x, tx = tid & 15, ty = tid >> 4;
  for (int i = tid; i < 288; i += 256) wl[i] = w1[i];   // FIX: 288 > 256, strided load
  for (int i = tid; i < 400; i += 256){
    int iy = i / 20, ix = i % 20;
    int gy = ty0 + iy - 2, gx = tx0 + ix - 2;
    float v = 0.f;
    if ((unsigned)gy < 256u && (unsigned)gx < 256u)
      v = __fdiv_rn((float)lbp[((size_t)b << 16) + (gy << 8) + gx], 255.0f);
    lt[iy][ix] = v;
  }
  __syncthreads();
  // recompute y1 halo tile: y1h[oc][jy][jx] = relu(bn1(conv1)) at global (ty0+jy-1, tx0+jx-1)
  for (int i = tid; i < 324; i += 256){
    int jy = i / 18, jx = i % 18;
    int gy = ty0 + jy - 1, gx = tx0 + jx - 1;
    bool in = ((unsigned)gy < 256u) && ((unsigned)gx < 256u);
    float v[9];
    #pragma unroll
    for (int j = 0; j < 9; ++j) v[j] = lt[jy + j/3][jx + j%3];
    #pragma unroll
    for (int oc = 0; oc < 32; ++oc){
      float a = 0.f;
      #pragma unroll
      for (int j = 0; j < 9; ++j) a = fmaf(v[j], wl[oc*9 + j], a);
      y1h[oc][jy][jx] = in ? fmaxf(fmaf(a, st1[oc], st1[32 + oc]), 0.f) : 0.f;
    }
  }
  __syncthreads();
  float acc[64];
  #pragma unroll
  for (int oc = 0; oc < 64; ++oc) acc[oc] = 0.f;
  for (int ic = 0; ic < 32; ++ic){
    #pragma unroll
    for (int tap = 0; tap < 9; ++tap){
      float vv = y1h[ic][ty + tap/3][tx + tap%3];
      const float* wb = w2t + (ic*9 + tap)*64;   // wave-uniform -> scalar loads
      #pragma unroll
      for (int oc = 0; oc < 64; ++oc) acc[oc] = fmaf(vv, wb[oc], acc[oc]);
    }
  }
  if (MODE == 0){
    int blk = (blockIdx.z * 16 + blockIdx.y) * 16 + blockIdx.x;
    block_stats<64>(acc, red, tid, part2 + (size_t)blk * 128);
  } else {
    int Y = (ty0 + ty) >> 1, X = (tx0 + tx) >> 1;
    bool wr = ((tx & 1) == 0) && ((ty & 1) == 0);
    #pragma unroll
    for (int oc = 0; oc < 64; ++oc){
      float r2 = fmaxf(fmaf(acc[oc], st2[oc], st2[64 + oc]), 0.f);
      float m = fmaxf(r2, __shfl_xor(r2, 1));    // x-pair (tid^1)
      m = fmaxf(m, __shfl_xor(m, 16));           // y-pair (tid^16), same wave
      if (wr) out[(((size_t)b*64 + oc) << 14) + (Y << 7) + X] = m;
    }
  }
}

extern "C" void kernel_launch(void* const* d_in, const int* in_sizes, int n_in,
                              void* d_out, int out_size, void* d_ws, size_t ws_size,
                              hipStream_t stream){
  const float* img = (const float*)d_in[0];
  const float* w1  = (const float*)d_in[1];
  const float* g1  = (const float*)d_in[3];
  const float* be1 = (const float*)d_in[4];
  const float* w2  = (const float*)d_in[5];
  const float* g2  = (const float*)d_in[7];
  const float* be2 = (const float*)d_in[8];
  float* out = (float*)d_out;

  // compact workspace: ~3.2 MB total (no y1/y2 materialization)
  char* base = (char*)d_ws;
  u8*    q    = (u8*)(base + 0);
  u8*    filt = (u8*)(base + 524288);
  u8*    lbp  = (u8*)(base + 1048576);
  float* w2t  = (float*)(base + 1572864);            // 73728 B
  float* p1   = (float*)(base + 1646592);            // 524288 B
  float* p2   = (float*)(base + 2170880);            // 1048576 B
  float* st1  = (float*)(base + 3219456);            // 256 B
  float* st2  = (float*)(base + 3219712);            // 512 B

  k_gray     <<<2048, 256, 0, stream>>>(img, q);
  k_bilateral<<<dim3(8,8,8), 256, 0, stream>>>(q, filt);
  k_lbp      <<<2048, 256, 0, stream>>>(filt, lbp);
  k_w2t      <<<72, 256, 0, stream>>>(w2, w2t);
  k_stats1   <<<dim3(16,16,8), 256, 0, stream>>>(lbp, w1, p1);
  k_stats    <<<32, 256, 0, stream>>>(p1, 64, 32, g1, be1, st1);
  k_fused<0> <<<dim3(16,16,8), 256, 0, stream>>>(lbp, w1, w2t, st1, st2, p2, out);
  k_stats    <<<64, 256, 0, stream>>>(p2, 128, 64, g2, be2, st2);
  k_fused<1> <<<dim3(16,16,8), 256, 0, stream>>>(lbp, w1, w2t, st1, st2, p2, out);
}

// Round 6
// 328.023 us; speedup vs baseline: 4.2000x; 4.2000x over previous
//
#include <hip/hip_runtime.h>
#include <math.h>

#define RAD 15
#define DIAM 31

typedef unsigned char u8;
typedef unsigned short ushort_t;
typedef __attribute__((ext_vector_type(8))) short bf16x8;
typedef __attribute__((ext_vector_type(4))) float f32x4;

__device__ __forceinline__ unsigned short f2bf(float f){   // RNE float->bf16 (finite)
  unsigned u = __float_as_uint(f);
  return (unsigned short)((u + 0x7FFFu + ((u >> 16) & 1u)) >> 16);
}

// ---------------- gray + quantize (fp32, exact ref op order) ----------------
__global__ __launch_bounds__(256) void k_gray(const float* __restrict__ img, u8* __restrict__ q){
  int i = blockIdx.x*256 + threadIdx.x;            // 8*256*256 = 524288
  int b = i >> 16, p = i & 65535;
  const float* pb = img + (((size_t)b*3) << 16);
  float r = pb[p], g = pb[65536 + p], bl = pb[131072 + p];
  float gray = __fadd_rn(__fadd_rn(__fmul_rn(0.299f, r), __fmul_rn(0.587f, g)), __fmul_rn(0.116f, bl));
  float t = floorf(__fmul_rn(gray, 255.0f));
  t = fminf(fmaxf(t, 0.0f), 255.0f);
  q[i] = (u8)(int)t;
}

// ---------------- bilateral: fp32 accumulation in exact ref scan order ----------------
__global__ __launch_bounds__(256) void k_bilateral(const u8* __restrict__ q, u8* __restrict__ filt){
  __shared__ int tile[62][62];
  __shared__ float swt[DIAM*DIAM];
  __shared__ float wc[256];
  int b = blockIdx.z;
  int gx0 = blockIdx.x * 32, gy0 = blockIdx.y * 32;
  int tid = threadIdx.x;
  const float inv2sc2 = (float)(-0.5/5625.0);
  const u8* qb = q + ((size_t)b << 16);
  for (int i = tid; i < DIAM*DIAM; i += 256){
    int dx = i / DIAM - RAD, dy = i % DIAM - RAD;
    int r2 = dx*dx + dy*dy;
    swt[i] = (r2 <= RAD*RAD) ? (float)exp(-0.5 * (double)r2 / 225.0) : 0.0f;
  }
  if (tid < 256){
    float df = (float)tid;
    float t = __fmul_rn(__fmul_rn(inv2sc2, df), df);
    wc[tid] = (float)exp((double)t);                  // correctly-rounded f32 exp
  }
  for (int i = tid; i < 62*62; i += 256){
    int ly = i / 62, lx = i % 62;
    int gy = gy0 + ly - RAD, gx = gx0 + lx - RAD;
    gy = gy < 0 ? -gy : (gy > 255 ? 510 - gy : gy);   // jnp.pad reflect
    gx = gx < 0 ? -gx : (gx > 255 ? 510 - gx : gx);
    tile[ly][lx] = (int)qb[(gy << 8) + gx];
  }
  __syncthreads();
  int tx = tid & 31, ty0 = tid >> 5;
  int c[4]; float num[4], den[4];
  #pragma unroll
  for (int k = 0; k < 4; ++k){
    c[k] = tile[ty0 + 8*k + RAD][tx + RAD];
    num[k] = 0.f; den[k] = 0.f;
  }
  for (int dx = -RAD; dx <= RAD; ++dx){
    for (int dy = -RAD; dy <= RAD; ++dy){
      int r2 = dx*dx + dy*dy;
      if (r2 > RAD*RAD) continue;
      float sw = swt[(dx+RAD)*DIAM + (dy+RAD)];
      #pragma unroll
      for (int k = 0; k < 4; ++k){
        int sh = tile[ty0 + 8*k + dx + RAD][tx + dy + RAD];
        int d = sh - c[k]; d = d < 0 ? -d : d;
        float w = __fmul_rn(sw, wc[d]);
        num[k] = __fadd_rn(num[k], __fmul_rn(w, (float)sh));
        den[k] = __fadd_rn(den[k], w);
      }
    }
  }
  #pragma unroll
  for (int k = 0; k < 4; ++k){
    int gy = gy0 + ty0 + 8*k, gx = gx0 + tx;
    filt[((size_t)b << 16) + (gy << 8) + gx] = (u8)(int)rintf(__fdiv_rn(num[k], den[k]));
  }
}

// ---------------- LBP code (exact integer compares) ----------------
__global__ __launch_bounds__(256) void k_lbp(const u8* __restrict__ filt, u8* __restrict__ lbp){
  int i = blockIdx.x*256 + threadIdx.x;
  int b = i >> 16, p = i & 65535, y = p >> 8, x = p & 255;
  int v = 0;
  if (y > 0 && y < 255 && x > 0 && x < 255){
    const u8* f = filt + ((size_t)b << 16);
    int c = f[(y << 8) + x];
    int pat = 128;
    pat += (f[((y+1) << 8) + x]     >= c) ? 1  : 0;
    pat += (f[(y << 8) + x - 1]     >= c) ? 6  : 0;
    pat += (f[((y-1) << 8) + x - 1] >= c) ? 8  : 0;
    pat += (f[((y-1) << 8) + x]     >= c) ? 48 : 0;
    pat += (f[(y << 8) + x + 1]     >= c) ? 64 : 0;
    v = pat;
  }
  lbp[i] = (u8)v;
}

// ---------------- per-block channel stats helper (conv1 pass) ----------------
template<int OC>
__device__ __forceinline__ void block_stats(const float* acc, float* red, int tid, float* out){
  #pragma unroll
  for (int c0 = 0; c0 < OC; c0 += 8){
    #pragma unroll
    for (int pass = 0; pass < 2; ++pass){
      __syncthreads();
      #pragma unroll
      for (int j = 0; j < 8; ++j){
        float v = acc[c0 + j];
        red[tid*8 + j] = pass ? __fmul_rn(v, v) : v;
      }
      __syncthreads();
      int i = tid >> 5, s = tid & 31;
      float v = 0.f;
      #pragma unroll
      for (int k = 0; k < 8; ++k) v += red[(s + 32*k)*8 + i];
      v += __shfl_xor(v, 1); v += __shfl_xor(v, 2); v += __shfl_xor(v, 4);
      v += __shfl_xor(v, 8); v += __shfl_xor(v, 16);
      if (s == 0) out[2*(c0 + i) + pass] = v;
    }
  }
}

// ---------------- pass A: conv1 stats only ----------------
__global__ __launch_bounds__(256) void k_stats1(const u8* __restrict__ lbp, const float* __restrict__ w1,
                                                float* __restrict__ part1){
  __shared__ float t[18][18];
  __shared__ float wl[288];
  __shared__ float red[2048];
  int b = blockIdx.z;
  int ty0 = blockIdx.y * 16, tx0 = blockIdx.x * 16;
  int tid = threadIdx.x, tx = tid & 15, ty = tid >> 4;
  for (int i = tid; i < 288; i += 256) wl[i] = w1[i];
  for (int i = tid; i < 324; i += 256){
    int iy = i / 18, ix = i % 18;
    int gy = ty0 + iy - 1, gx = tx0 + ix - 1;
    float v = 0.f;
    if ((unsigned)gy < 256u && (unsigned)gx < 256u)
      v = __fdiv_rn((float)lbp[((size_t)b << 16) + (gy << 8) + gx], 255.0f);
    t[iy][ix] = v;
  }
  __syncthreads();
  float v[9];
  #pragma unroll
  for (int j = 0; j < 9; ++j) v[j] = t[ty + j/3][tx + j%3];
  float acc[32];
  #pragma unroll
  for (int oc = 0; oc < 32; ++oc){
    float a = 0.f;
    #pragma unroll
    for (int j = 0; j < 9; ++j) a = fmaf(v[j], wl[oc*9 + j], a);
    acc[oc] = a;
  }
  int blk = (blockIdx.z * 16 + blockIdx.y) * 16 + blockIdx.x;
  block_stats<32>(acc, red, tid, part1 + (size_t)blk * 64);
}

// ---------------- finalize BN stats ----------------
__global__ __launch_bounds__(256) void k_stats(const float* __restrict__ part, int stride, int OC,
                                               const float* __restrict__ g, const float* __restrict__ beta,
                                               float* __restrict__ st){
  int ch = blockIdx.x, tid = threadIdx.x;
  double s = 0.0, s2 = 0.0;
  for (int k = tid; k < 2048; k += 256){
    const float* pp = part + (size_t)k * stride + 2*ch;
    s += (double)pp[0]; s2 += (double)pp[1];
  }
  #pragma unroll
  for (int m = 1; m <= 32; m <<= 1){ s += __shfl_xor(s, m); s2 += __shfl_xor(s2, m); }
  __shared__ double red[8];
  if ((tid & 63) == 0){ red[(tid >> 6)*2] = s; red[(tid >> 6)*2 + 1] = s2; }
  __syncthreads();
  if (tid == 0){
    s  = red[0] + red[2] + red[4] + red[6];
    s2 = red[1] + red[3] + red[5] + red[7];
    double mean = s / 524288.0;
    double var  = s2 / 524288.0 - mean*mean;
    double rs   = 1.0 / sqrt(var + 1e-5);
    double sc   = (double)g[ch] * rs;
    st[ch]      = (float)sc;
    st[OC + ch] = (float)((double)beta[ch] - mean * sc);
  }
}

// ---------------- w2 -> bf16 in MFMA B-fragment order ----------------
// frag fo = t*4+o (tap t, oc-group o); lane l holds B[k=(l>>4)*8+j][n=l&15], j=0..7
__global__ __launch_bounds__(256) void k_w2bf(const float* __restrict__ w2, ushort_t* __restrict__ w2b){
  int i = blockIdx.x*256 + threadIdx.x;   // 36*64*8 = 18432
  if (i < 18432){
    int j = i & 7, l = (i >> 3) & 63, fo = i >> 9;
    int t = fo >> 2, o = fo & 3;
    int oc = o*16 + (l & 15), ic = (l >> 4)*8 + j;
    w2b[i] = f2bf(w2[(oc*32 + ic)*9 + t]);
  }
}

// ---------------- fused conv1+bn1+relu+conv2 via bf16 MFMA ----------------
// 16x16 px tile/block, 4 waves; wave w owns rows [4w,4w+4); per wave: 4 pxg x 4 ocg x 9 taps MFMA.
// MODE 0: partial stats2; MODE 1: bn2+relu+2x2 maxpool -> out
#define SM_Y1   0                       // ushort[18*18*40] = 25920 B (pad 40: 2-way-free banks)
#define SM_W2   25920                   // ushort[36*64*8]  = 36864 B
#define SM_LT   62784                   // float[400] = 1600 B
#define SM_WL   64384                   // float[288] = 1152 B
#define SM_RED  62784                   // float[512] (alias over LT/WL, post-conv2)
template<int MODE>
__global__ __launch_bounds__(256) void k_fused(const u8* __restrict__ lbp, const float* __restrict__ w1,
                                               const ushort_t* __restrict__ w2b,
                                               const float* __restrict__ st1, const float* __restrict__ st2,
                                               float* __restrict__ part2, float* __restrict__ out){
  __shared__ __align__(16) u8 smem[65536];
  ushort_t* y1h = (ushort_t*)(smem + SM_Y1);
  ushort_t* w2s = (ushort_t*)(smem + SM_W2);
  float*    lt  = (float*)(smem + SM_LT);
  float*    wl  = (float*)(smem + SM_WL);
  int b = blockIdx.z;
  int ty0 = blockIdx.y * 16, tx0 = blockIdx.x * 16;
  int tid = threadIdx.x;
  // ---- stage: w1, w2-frags, lbp tile ----
  for (int i = tid; i < 288; i += 256) wl[i] = w1[i];
  for (int i = tid; i < 2304; i += 256) ((uint4*)w2s)[i] = ((const uint4*)w2b)[i];
  for (int i = tid; i < 400; i += 256){
    int iy = i / 20, ix = i % 20;
    int gy = ty0 + iy - 2, gx = tx0 + ix - 2;
    float v = 0.f;
    if ((unsigned)gy < 256u && (unsigned)gx < 256u)
      v = __fdiv_rn((float)lbp[((size_t)b << 16) + (gy << 8) + gx], 255.0f);
    lt[i] = v;
  }
  __syncthreads();
  // ---- conv1 + bn1 + relu -> y1h bf16 [18][18][40] ----
  for (int i = tid; i < 324; i += 256){
    int jy = i / 18, jx = i % 18;
    int gy = ty0 + jy - 1, gx = tx0 + jx - 1;
    bool in = ((unsigned)gy < 256u) && ((unsigned)gx < 256u);
    float v[9];
    #pragma unroll
    for (int j = 0; j < 9; ++j) v[j] = lt[(jy + j/3)*20 + jx + j%3];
    ushort_t* row = y1h + i*40;
    #pragma unroll
    for (int o2 = 0; o2 < 16; ++o2){
      float a0 = 0.f, a1 = 0.f;
      #pragma unroll
      for (int j = 0; j < 9; ++j){
        a0 = fmaf(v[j], wl[(2*o2  )*9 + j], a0);
        a1 = fmaf(v[j], wl[(2*o2+1)*9 + j], a1);
      }
      float r0 = in ? fmaxf(fmaf(a0, st1[2*o2  ], st1[32 + 2*o2  ]), 0.f) : 0.f;
      float r1 = in ? fmaxf(fmaf(a1, st1[2*o2+1], st1[32 + 2*o2+1]), 0.f) : 0.f;
      *(unsigned int*)(row + o2*2) = (unsigned int)f2bf(r0) | ((unsigned int)f2bf(r1) << 16);
    }
  }
  __syncthreads();
  // ---- conv2: 144 MFMA/wave ----
  int lane = tid & 63, w = tid >> 6;
  int mA = lane & 15, g = lane >> 4;          // A-operand: row=mA, k-group=g
  int pyA = mA >> 2, pxA = mA & 3;
  f32x4 acc[4][4] = {};                        // [pxg_i][ocg]
  #pragma unroll
  for (int t = 0; t < 9; ++t){
    int dy = t/3, dx = t%3;
    bf16x8 bf[4];
    #pragma unroll
    for (int o = 0; o < 4; ++o) bf[o] = *(const bf16x8*)(w2s + (((t*4 + o) << 6) + lane)*8);
    #pragma unroll
    for (int i = 0; i < 4; ++i){
      int jy = (w << 2) + pyA + dy, jx = (i << 2) + pxA + dx;
      bf16x8 a = *(const bf16x8*)(y1h + (jy*18 + jx)*40 + g*8);
      #pragma unroll
      for (int o = 0; o < 4; ++o)
        acc[i][o] = __builtin_amdgcn_mfma_f32_16x16x32_bf16(a, bf[o], acc[i][o], 0, 0, 0);
    }
  }
  // C layout: pixel m = 4*g + r (py=g, px=r), col = lane&15 = oc within group
  int col = lane & 15;
  if (MODE == 0){
    float* red = (float*)(smem + SM_RED);      // aliases lt/wl (dead now)
    float s[4], s2[4];
    #pragma unroll
    for (int o = 0; o < 4; ++o){
      s[o] = 0.f; s2[o] = 0.f;
      #pragma unroll
      for (int i = 0; i < 4; ++i)
        #pragma unroll
        for (int r = 0; r < 4; ++r){
          float v = acc[i][o][r];
          s[o] += v; s2[o] = fmaf(v, v, s2[o]);
        }
      s[o]  += __shfl_xor(s[o], 16);  s[o]  += __shfl_xor(s[o], 32);
      s2[o] += __shfl_xor(s2[o], 16); s2[o] += __shfl_xor(s2[o], 32);
    }
    if (g == 0){
      #pragma unroll
      for (int o = 0; o < 4; ++o){
        red[((0*4 + w)*4 + o)*16 + col] = s[o];
        red[((1*4 + w)*4 + o)*16 + col] = s2[o];
      }
    }
    __syncthreads();
    if (tid < 128){
      int stat = tid >> 6, oc = tid & 63, o = oc >> 4, c = oc & 15;
      float* red2 = (float*)(smem + SM_RED);
      float sum = 0.f;
      #pragma unroll
      for (int ww = 0; ww < 4; ++ww) sum += red2[((stat*4 + ww)*4 + o)*16 + c];
      int blk = (blockIdx.z * 16 + blockIdx.y) * 16 + blockIdx.x;
      part2[(size_t)blk * 128 + 2*oc + stat] = sum;
    }
  } else {
    __syncthreads();                           // y1h reads done; reuse as pool buffer
    float* pool = (float*)(smem + SM_Y1);      // [64 oc][64 px] = 16 KB
    #pragma unroll
    for (int o = 0; o < 4; ++o){
      int oc = (o << 4) + col;
      float sc = st2[oc], sh = st2[64 + oc];
      #pragma unroll
      for (int i = 0; i < 4; ++i){
        float v0 = fmaxf(fmaf(acc[i][o][0], sc, sh), 0.f);
        float v1 = fmaxf(fmaf(acc[i][o][1], sc, sh), 0.f);
        float v2 = fmaxf(fmaf(acc[i][o][2], sc, sh), 0.f);
        float v3 = fmaxf(fmaf(acc[i][o][3], sc, sh), 0.f);
        float h0 = fmaxf(v0, v1), h2 = fmaxf(v2, v3);      // horiz pairs (px=r)
        float p0 = fmaxf(h0, __shfl_xor(h0, 16));           // vert pair: py=g, g^1
        float p2 = fmaxf(h2, __shfl_xor(h2, 16));
        if (!(g & 1)){
          float2 pv = make_float2(p0, p2);
          *(float2*)&pool[oc*64 + (w*2 + (g >> 1))*8 + i*2] = pv;
        }
      }
    }
    __syncthreads();
    int Y0 = blockIdx.y * 8, X0 = blockIdx.x * 8;
    for (int k = tid; k < 1024; k += 256){
      int oc = k >> 4, quad = k & 15;
      int row = quad >> 1, c4 = (quad & 1) * 4;
      float4 v = *(float4*)&pool[oc*64 + quad*4];
      *(float4*)&out[(((size_t)b*64 + oc) << 14) + (size_t)(Y0 + row)*128 + X0 + c4] = v;
    }
  }
}

extern "C" void kernel_launch(void* const* d_in, const int* in_sizes, int n_in,
                              void* d_out, int out_size, void* d_ws, size_t ws_size,
                              hipStream_t stream){
  const float* img = (const float*)d_in[0];
  const float* w1  = (const float*)d_in[1];
  const float* g1  = (const float*)d_in[3];
  const float* be1 = (const float*)d_in[4];
  const float* w2  = (const float*)d_in[5];
  const float* g2  = (const float*)d_in[7];
  const float* be2 = (const float*)d_in[8];
  float* out = (float*)d_out;

  // compact workspace ~3.1 MB
  char* base = (char*)d_ws;
  u8*       q    = (u8*)(base + 0);
  u8*       filt = (u8*)(base + 524288);
  u8*       lbp  = (u8*)(base + 1048576);
  ushort_t* w2b  = (ushort_t*)(base + 1572864);   // 36864 B
  float*    p1   = (float*)(base + 1609728);      // 524288 B
  float*    p2   = (float*)(base + 2134016);      // 1048576 B
  float*    st1  = (float*)(base + 3182592);      // 256 B
  float*    st2  = (float*)(base + 3182848);      // 512 B

  k_gray     <<<2048, 256, 0, stream>>>(img, q);
  k_bilateral<<<dim3(8,8,8), 256, 0, stream>>>(q, filt);
  k_lbp      <<<2048, 256, 0, stream>>>(filt, lbp);
  k_w2bf     <<<72, 256, 0, stream>>>(w2, w2b);
  k_stats1   <<<dim3(16,16,8), 256, 0, stream>>>(lbp, w1, p1);
  k_stats    <<<32, 256, 0, stream>>>(p1, 64, 32, g1, be1, st1);
  k_fused<0> <<<dim3(16,16,8), 256, 0, stream>>>(lbp, w1, w2b, st1, st2, p2, out);
  k_stats    <<<64, 256, 0, stream>>>(p2, 128, 64, g2, be2, st2);
  k_fused<1> <<<dim3(16,16,8), 256, 0, stream>>>(lbp, w1, w2b, st1, st2, p2, out);
}

// Round 7
// 238.022 us; speedup vs baseline: 5.7881x; 1.3781x over previous
//
#include <hip/hip_runtime.h>
#include <math.h>

#define RAD 15
#define DIAM 31

typedef unsigned char u8;
typedef unsigned short ushort_t;
typedef __attribute__((ext_vector_type(8))) short bf16x8;
typedef __attribute__((ext_vector_type(4))) float f32x4;

__device__ __forceinline__ unsigned short f2bf(float f){
  unsigned u = __float_as_uint(f);
  return (unsigned short)((u + 0x7FFFu + ((u >> 16) & 1u)) >> 16);
}

// ---------------- gray + quantize ----------------
__global__ __launch_bounds__(256) void k_gray(const float* __restrict__ img, u8* __restrict__ q){
  int i = blockIdx.x*256 + threadIdx.x;
  int b = i >> 16, p = i & 65535;
  const float* pb = img + (((size_t)b*3) << 16);
  float r = pb[p], g = pb[65536 + p], bl = pb[131072 + p];
  float gray = __fadd_rn(__fadd_rn(__fmul_rn(0.299f, r), __fmul_rn(0.587f, g)), __fmul_rn(0.116f, bl));
  float t = floorf(__fmul_rn(gray, 255.0f));
  t = fminf(fmaxf(t, 0.0f), 255.0f);
  q[i] = (u8)(int)t;
}

// ---------------- prep: w2 frags + exp tables ----------------
__global__ __launch_bounds__(256) void k_prep(const float* __restrict__ w2, ushort_t* __restrict__ w2b,
                                              float* __restrict__ wc_g, float* __restrict__ swt_g){
  int blk = blockIdx.x, tid = threadIdx.x;
  if (blk < 72){
    int i = blk*256 + tid;
    int j = i & 7, l = (i >> 3) & 63, fo = i >> 9;
    int t = fo >> 2, o = fo & 3;
    int oc = o*16 + (l & 15), ic = (l >> 4)*8 + j;
    w2b[i] = f2bf(w2[(oc*32 + ic)*9 + t]);
  } else {
    const float inv2sc2 = (float)(-0.5/5625.0);
    float df = (float)tid;
    float t = __fmul_rn(__fmul_rn(inv2sc2, df), df);
    wc_g[tid] = (float)exp((double)t);                 // correctly-rounded f32 exp
    for (int i = tid; i < DIAM*DIAM; i += 256){
      int dx = i / DIAM - RAD, dy = i % DIAM - RAD;
      int r2 = dx*dx + dy*dy;
      swt_g[i] = (r2 <= RAD*RAD) ? (float)exp(-0.5 * (double)r2 / 225.0) : 0.0f;
    }
  }
}

// ---------------- bilateral: register-cached rows + bank-replicated wc ----------------
// 32x32 px tile, 4 horizontal px/thread (x0 = 4*(tid&7), dword-aligned window).
// Per dx: 9 aligned b32 LDS reads cover all dy/px byte extracts (static indices).
// wc gather: wcr[d*32 + lane&31] -> each lane its own bank -> conflict-free.
// Accumulation order/value bit-identical to reference (dx-major, dy inner, skip r2>225).
__global__ __launch_bounds__(256) void k_bilateral(const u8* __restrict__ q, u8* __restrict__ filt,
                                                   const float* __restrict__ wc_g,
                                                   const float* __restrict__ swt_g){
  __shared__ __align__(16) u8 sm[32768 + 62*68];
  float* wcr  = (float*)sm;                 // [256][32] replicated
  u8*   tileB = sm + 32768;                 // [62][68] halo tile (stride 68)
  int b = blockIdx.z;
  int gx0 = blockIdx.x * 32, gy0 = blockIdx.y * 32;
  int tid = threadIdx.x;
  const u8* qb = q + ((size_t)b << 16);
  { // stage replicated wc: thread d writes 32 copies (one-time)
    float v = wc_g[tid];
    float4 v4 = make_float4(v, v, v, v);
    #pragma unroll
    for (int k = 0; k < 8; ++k) *(float4*)&wcr[tid*32 + k*4] = v4;
  }
  for (int i = tid; i < 62*62; i += 256){
    int ly = i / 62, lx = i % 62;
    int gy = gy0 + ly - RAD, gx = gx0 + lx - RAD;
    gy = gy < 0 ? -gy : (gy > 255 ? 510 - gy : gy);   // jnp.pad reflect
    gx = gx < 0 ? -gx : (gx > 255 ? 510 - gx : gx);
    tileB[ly*68 + lx] = qb[(gy << 8) + gx];
  }
  __syncthreads();
  int tx8 = tid & 7, r = tid >> 3;          // 8 col-groups x 32 rows
  int lk = (tid & 31);
  int cbase = (r + RAD)*68 + RAD + 4*tx8;
  float c_f[4], num[4], den[4];
  #pragma unroll
  for (int p = 0; p < 4; ++p){
    c_f[p] = (float)tileB[cbase + p];
    num[p] = 0.f; den[p] = 0.f;
  }
  #pragma unroll 1
  for (int dx = -RAD; dx <= RAD; ++dx){
    int dxx = dx*dx;
    int rowoff = (r + dx + RAD)*68 + 4*tx8;
    unsigned wrow[9];
    #pragma unroll
    for (int k = 0; k < 9; ++k) wrow[k] = *(const unsigned*)(tileB + rowoff + 4*k);
    const float* swrow = swt_g + (dx + RAD)*DIAM + RAD;
    #pragma unroll
    for (int DY = -RAD; DY <= RAD; ++DY){
      if (dxx + DY*DY <= RAD*RAD){
        float sw = swrow[DY];               // wave-uniform -> scalar load
        #pragma unroll
        for (int p = 0; p < 4; ++p){
          const int B = RAD + p + DY;       // 0..33, compile-time
          float shf = (float)((wrow[B >> 2] >> ((B & 3)*8)) & 255u);
          float diff = __fsub_rn(shf, c_f[p]);              // exact (small ints)
          int idx = (int)fabsf(diff);
          float wcd = wcr[(idx << 5) + lk];                 // conflict-free gather
          float w = __fmul_rn(sw, wcd);
          num[p] = __fadd_rn(num[p], __fmul_rn(w, shf));
          den[p] = __fadd_rn(den[p], w);
        }
      }
    }
  }
  unsigned pack = 0;
  #pragma unroll
  for (int p = 0; p < 4; ++p)
    pack |= ((unsigned)(int)rintf(__fdiv_rn(num[p], den[p]))) << (p*8);
  int gy = gy0 + r, gx = gx0 + 4*tx8;
  *(unsigned*)(filt + ((size_t)b << 16) + (gy << 8) + gx) = pack;
}

// ---------------- LBP ----------------
__global__ __launch_bounds__(256) void k_lbp(const u8* __restrict__ filt, u8* __restrict__ lbp){
  int i = blockIdx.x*256 + threadIdx.x;
  int b = i >> 16, p = i & 65535, y = p >> 8, x = p & 255;
  int v = 0;
  if (y > 0 && y < 255 && x > 0 && x < 255){
    const u8* f = filt + ((size_t)b << 16);
    int c = f[(y << 8) + x];
    int pat = 128;
    pat += (f[((y+1) << 8) + x]     >= c) ? 1  : 0;
    pat += (f[(y << 8) + x - 1]     >= c) ? 6  : 0;
    pat += (f[((y-1) << 8) + x - 1] >= c) ? 8  : 0;
    pat += (f[((y-1) << 8) + x]     >= c) ? 48 : 0;
    pat += (f[(y << 8) + x + 1]     >= c) ? 64 : 0;
    v = pat;
  }
  lbp[i] = (u8)v;
}

// ---------------- per-block channel stats (conv1 pass) ----------------
template<int OC>
__device__ __forceinline__ void block_stats(const float* acc, float* red, int tid, float* out){
  #pragma unroll
  for (int c0 = 0; c0 < OC; c0 += 8){
    #pragma unroll
    for (int pass = 0; pass < 2; ++pass){
      __syncthreads();
      #pragma unroll
      for (int j = 0; j < 8; ++j){
        float v = acc[c0 + j];
        red[tid*8 + j] = pass ? __fmul_rn(v, v) : v;
      }
      __syncthreads();
      int i = tid >> 5, s = tid & 31;
      float v = 0.f;
      #pragma unroll
      for (int k = 0; k < 8; ++k) v += red[(s + 32*k)*8 + i];
      v += __shfl_xor(v, 1); v += __shfl_xor(v, 2); v += __shfl_xor(v, 4);
      v += __shfl_xor(v, 8); v += __shfl_xor(v, 16);
      if (s == 0) out[2*(c0 + i) + pass] = v;
    }
  }
}

// ---------------- pass A: conv1 stats only ----------------
__global__ __launch_bounds__(256) void k_stats1(const u8* __restrict__ lbp, const float* __restrict__ w1,
                                                float* __restrict__ part1){
  __shared__ float t[18][18];
  __shared__ float wl[288];
  __shared__ float red[2048];
  int b = blockIdx.z;
  int ty0 = blockIdx.y * 16, tx0 = blockIdx.x * 16;
  int tid = threadIdx.x, tx = tid & 15, ty = tid >> 4;
  for (int i = tid; i < 288; i += 256) wl[i] = w1[i];
  for (int i = tid; i < 324; i += 256){
    int iy = i / 18, ix = i % 18;
    int gy = ty0 + iy - 1, gx = tx0 + ix - 1;
    float v = 0.f;
    if ((unsigned)gy < 256u && (unsigned)gx < 256u)
      v = __fdiv_rn((float)lbp[((size_t)b << 16) + (gy << 8) + gx], 255.0f);
    t[iy][ix] = v;
  }
  __syncthreads();
  float v[9];
  #pragma unroll
  for (int j = 0; j < 9; ++j) v[j] = t[ty + j/3][tx + j%3];
  float acc[32];
  #pragma unroll
  for (int oc = 0; oc < 32; ++oc){
    float a = 0.f;
    #pragma unroll
    for (int j = 0; j < 9; ++j) a = fmaf(v[j], wl[oc*9 + j], a);
    acc[oc] = a;
  }
  int blk = (blockIdx.z * 16 + blockIdx.y) * 16 + blockIdx.x;
  block_stats<32>(acc, red, tid, part1 + (size_t)blk * 64);
}

// ---------------- finalize BN stats ----------------
__global__ __launch_bounds__(256) void k_stats(const float* __restrict__ part, int stride, int OC,
                                               const float* __restrict__ g, const float* __restrict__ beta,
                                               float* __restrict__ st){
  int ch = blockIdx.x, tid = threadIdx.x;
  double s = 0.0, s2 = 0.0;
  for (int k = tid; k < 2048; k += 256){
    const float* pp = part + (size_t)k * stride + 2*ch;
    s += (double)pp[0]; s2 += (double)pp[1];
  }
  #pragma unroll
  for (int m = 1; m <= 32; m <<= 1){ s += __shfl_xor(s, m); s2 += __shfl_xor(s2, m); }
  __shared__ double red[8];
  if ((tid & 63) == 0){ red[(tid >> 6)*2] = s; red[(tid >> 6)*2 + 1] = s2; }
  __syncthreads();
  if (tid == 0){
    s  = red[0] + red[2] + red[4] + red[6];
    s2 = red[1] + red[3] + red[5] + red[7];
    double mean = s / 524288.0;
    double var  = s2 / 524288.0 - mean*mean;
    double rs   = 1.0 / sqrt(var + 1e-5);
    double sc   = (double)g[ch] * rs;
    st[ch]      = (float)sc;
    st[OC + ch] = (float)((double)beta[ch] - mean * sc);
  }
}

// ---------------- fused conv1+bn1+relu+conv2 (bf16 MFMA) ----------------
// LDS 28KB (B-frags straight from global/L2) -> 3+ blocks/CU.
// y1h writes as b128 (conflict-free span tiling); pool stride 66 (conflict-free).
#define SM_Y1   0                       // ushort[324][40] = 25920 B
#define SM_LT   25920                   // float[400] = 1600 B
#define SM_WL   27520                   // float[288] = 1152 B
#define SM_RED  25920                   // float[512] alias (lt/wl dead post-conv1)
template<int MODE>
__global__ __launch_bounds__(256) void k_fused(const u8* __restrict__ lbp, const float* __restrict__ w1,
                                               const ushort_t* __restrict__ w2b,
                                               const float* __restrict__ st1, const float* __restrict__ st2,
                                               float* __restrict__ part2, float* __restrict__ out){
  __shared__ __align__(16) u8 smem[28672];
  ushort_t* y1h = (ushort_t*)(smem + SM_Y1);
  float*    lt  = (float*)(smem + SM_LT);
  float*    wl  = (float*)(smem + SM_WL);
  int b = blockIdx.z;
  int ty0 = blockIdx.y * 16, tx0 = blockIdx.x * 16;
  int tid = threadIdx.x;
  for (int i = tid; i < 288; i += 256) wl[i] = w1[i];
  for (int i = tid; i < 400; i += 256){
    int iy = i / 20, ix = i % 20;
    int gy = ty0 + iy - 2, gx = tx0 + ix - 2;
    float v = 0.f;
    if ((unsigned)gy < 256u && (unsigned)gx < 256u)
      v = __fdiv_rn((float)lbp[((size_t)b << 16) + (gy << 8) + gx], 255.0f);
    lt[i] = v;
  }
  __syncthreads();
  // conv1 + bn1 + relu -> y1h bf16 [324][40], 16B-aligned b128 writes
  for (int i = tid; i < 324; i += 256){
    int jy = i / 18, jx = i % 18;
    int gy = ty0 + jy - 1, gx = tx0 + jx - 1;
    bool in = ((unsigned)gy < 256u) && ((unsigned)gx < 256u);
    float v[9];
    #pragma unroll
    for (int j = 0; j < 9; ++j) v[j] = lt[(jy + j/3)*20 + jx + j%3];
    ushort_t* row = y1h + i*40;
    #pragma unroll
    for (int o4 = 0; o4 < 4; ++o4){
      unsigned tmp[4];
      #pragma unroll
      for (int j2 = 0; j2 < 4; ++j2){
        int oc = o4*8 + j2*2;
        float a0 = 0.f, a1 = 0.f;
        #pragma unroll
        for (int j = 0; j < 9; ++j){
          a0 = fmaf(v[j], wl[(oc  )*9 + j], a0);
          a1 = fmaf(v[j], wl[(oc+1)*9 + j], a1);
        }
        float r0 = in ? fmaxf(fmaf(a0, st1[oc  ], st1[32 + oc  ]), 0.f) : 0.f;
        float r1 = in ? fmaxf(fmaf(a1, st1[oc+1], st1[32 + oc+1]), 0.f) : 0.f;
        tmp[j2] = (unsigned)f2bf(r0) | ((unsigned)f2bf(r1) << 16);
      }
      *(uint4*)(row + o4*8) = make_uint4(tmp[0], tmp[1], tmp[2], tmp[3]);
    }
  }
  __syncthreads();
  // conv2: B-frags from global (L2-hot), A-frags from LDS
  int lane = tid & 63, w = tid >> 6;
  int mA = lane & 15, g = lane >> 4;
  int pyA = mA >> 2, pxA = mA & 3;
  f32x4 acc[4][4] = {};
  #pragma unroll 3
  for (int t = 0; t < 9; ++t){
    int dy = t/3, dx = t%3;
    bf16x8 bf[4];
    #pragma unroll
    for (int o = 0; o < 4; ++o) bf[o] = *(const bf16x8*)(w2b + (((t*4 + o) << 6) + lane)*8);
    #pragma unroll
    for (int i = 0; i < 4; ++i){
      int jy = (w << 2) + pyA + dy, jx = (i << 2) + pxA + dx;
      bf16x8 a = *(const bf16x8*)(y1h + (jy*18 + jx)*40 + g*8);
      #pragma unroll
      for (int o = 0; o < 4; ++o)
        acc[i][o] = __builtin_amdgcn_mfma_f32_16x16x32_bf16(a, bf[o], acc[i][o], 0, 0, 0);
    }
  }
  int col = lane & 15;
  if (MODE == 0){
    float* red = (float*)(smem + SM_RED);
    float s[4], s2[4];
    #pragma unroll
    for (int o = 0; o < 4; ++o){
      s[o] = 0.f; s2[o] = 0.f;
      #pragma unroll
      for (int i = 0; i < 4; ++i)
        #pragma unroll
        for (int rr = 0; rr < 4; ++rr){
          float v = acc[i][o][rr];
          s[o] += v; s2[o] = fmaf(v, v, s2[o]);
        }
      s[o]  += __shfl_xor(s[o], 16);  s[o]  += __shfl_xor(s[o], 32);
      s2[o] += __shfl_xor(s2[o], 16); s2[o] += __shfl_xor(s2[o], 32);
    }
    if (g == 0){
      #pragma unroll
      for (int o = 0; o < 4; ++o){
        red[((0*4 + w)*4 + o)*16 + col] = s[o];
        red[((1*4 + w)*4 + o)*16 + col] = s2[o];
      }
    }
    __syncthreads();
    if (tid < 128){
      int stat = tid >> 6, oc = tid & 63, o = oc >> 4, c = oc & 15;
      float* red2 = (float*)(smem + SM_RED);
      float sum = 0.f;
      #pragma unroll
      for (int ww = 0; ww < 4; ++ww) sum += red2[((stat*4 + ww)*4 + o)*16 + c];
      int blk = (blockIdx.z * 16 + blockIdx.y) * 16 + blockIdx.x;
      part2[(size_t)blk * 128 + 2*oc + stat] = sum;
    }
  } else {
    __syncthreads();
    float* pool = (float*)(smem + SM_Y1);      // [64][66] padded
    #pragma unroll
    for (int o = 0; o < 4; ++o){
      int oc = (o << 4) + col;
      float sc = st2[oc], sh = st2[64 + oc];
      #pragma unroll
      for (int i = 0; i < 4; ++i){
        float v0 = fmaxf(fmaf(acc[i][o][0], sc, sh), 0.f);
        float v1 = fmaxf(fmaf(acc[i][o][1], sc, sh), 0.f);
        float v2 = fmaxf(fmaf(acc[i][o][2], sc, sh), 0.f);
        float v3 = fmaxf(fmaf(acc[i][o][3], sc, sh), 0.f);
        float h0 = fmaxf(v0, v1), h2 = fmaxf(v2, v3);
        float p0 = fmaxf(h0, __shfl_xor(h0, 16));
        float p2 = fmaxf(h2, __shfl_xor(h2, 16));
        if (!(g & 1)){
          *(float2*)&pool[oc*66 + (w*2 + (g >> 1))*8 + i*2] = make_float2(p0, p2);
        }
      }
    }
    __syncthreads();
    int Y0 = blockIdx.y * 8, X0 = blockIdx.x * 8;
    for (int k = tid; k < 1024; k += 256){
      int oc = k >> 4, quad = k & 15;
      int row = quad >> 1, c4 = (quad & 1) * 4;
      float4 v = *(float4*)&pool[oc*66 + quad*4];
      *(float4*)&out[(((size_t)b*64 + oc) << 14) + (size_t)(Y0 + row)*128 + X0 + c4] = v;
    }
  }
}

extern "C" void kernel_launch(void* const* d_in, const int* in_sizes, int n_in,
                              void* d_out, int out_size, void* d_ws, size_t ws_size,
                              hipStream_t stream){
  const float* img = (const float*)d_in[0];
  const float* w1  = (const float*)d_in[1];
  const float* g1  = (const float*)d_in[3];
  const float* be1 = (const float*)d_in[4];
  const float* w2  = (const float*)d_in[5];
  const float* g2  = (const float*)d_in[7];
  const float* be2 = (const float*)d_in[8];
  float* out = (float*)d_out;

  char* base = (char*)d_ws;                       // ~3.2 MB total
  u8*       q    = (u8*)(base + 0);
  u8*       filt = (u8*)(base + 524288);
  u8*       lbp  = (u8*)(base + 1048576);
  ushort_t* w2b  = (ushort_t*)(base + 1572864);   // 36864
  float*    wc_g = (float*)(base + 1609728);      // 1024
  float*    swtg = (float*)(base + 1610752);      // 3856
  float*    p1   = (float*)(base + 1614608);      // 524288
  float*    p2   = (float*)(base + 2138896);      // 1048576
  float*    st1  = (float*)(base + 3187472);      // 256
  float*    st2  = (float*)(base + 3187728);      // 512

  k_gray     <<<2048, 256, 0, stream>>>(img, q);
  k_prep     <<<73, 256, 0, stream>>>(w2, w2b, wc_g, swtg);
  k_bilateral<<<dim3(8,8,8), 256, 0, stream>>>(q, filt, wc_g, swtg);
  k_lbp      <<<2048, 256, 0, stream>>>(filt, lbp);
  k_stats1   <<<dim3(16,16,8), 256, 0, stream>>>(lbp, w1, p1);
  k_stats    <<<32, 256, 0, stream>>>(p1, 64, 32, g1, be1, st1);
  k_fused<0> <<<dim3(16,16,8), 256, 0, stream>>>(lbp, w1, w2b, st1, st2, p2, out);
  k_stats    <<<64, 256, 0, stream>>>(p2, 128, 64, g2, be2, st2);
  k_fused<1> <<<dim3(16,16,8), 256, 0, stream>>>(lbp, w1, w2b, st1, st2, p2, out);
}

// Round 9
// 206.699 us; speedup vs baseline: 6.6652x; 1.1515x over previous
//
#include <hip/hip_runtime.h>
#include <math.h>

#define RAD 15
#define DIAM 31

typedef unsigned char u8;
typedef unsigned short ushort_t;
typedef __attribute__((ext_vector_type(8))) short bf16x8;
typedef __attribute__((ext_vector_type(4))) float f32x4;

__device__ __forceinline__ unsigned short f2bf(float f){
  unsigned u = __float_as_uint(f);
  return (unsigned short)((u + 0x7FFFu + ((u >> 16) & 1u)) >> 16);
}

// ---------------- gray + quantize ----------------
__global__ __launch_bounds__(256) void k_gray(const float* __restrict__ img, u8* __restrict__ q){
  int i = blockIdx.x*256 + threadIdx.x;
  int b = i >> 16, p = i & 65535;
  const float* pb = img + (((size_t)b*3) << 16);
  float r = pb[p], g = pb[65536 + p], bl = pb[131072 + p];
  float gray = __fadd_rn(__fadd_rn(__fmul_rn(0.299f, r), __fmul_rn(0.587f, g)), __fmul_rn(0.116f, bl));
  float t = floorf(__fmul_rn(gray, 255.0f));
  t = fminf(fmaxf(t, 0.0f), 255.0f);
  q[i] = (u8)(int)t;
}

// ---------------- prep: w2 frags + exp tables ----------------
__global__ __launch_bounds__(256) void k_prep(const float* __restrict__ w2, ushort_t* __restrict__ w2b,
                                              float* __restrict__ wc_g, float* __restrict__ swt_g){
  int blk = blockIdx.x, tid = threadIdx.x;
  if (blk < 72){
    int i = blk*256 + tid;
    int j = i & 7, l = (i >> 3) & 63, fo = i >> 9;
    int t = fo >> 2, o = fo & 3;
    int oc = o*16 + (l & 15), ic = (l >> 4)*8 + j;
    w2b[i] = f2bf(w2[(oc*32 + ic)*9 + t]);
  } else {
    const float inv2sc2 = (float)(-0.5/5625.0);
    float df = (float)tid;
    float t = __fmul_rn(__fmul_rn(inv2sc2, df), df);
    wc_g[tid] = (float)exp((double)t);                 // correctly-rounded f32 exp
    for (int i = tid; i < DIAM*DIAM; i += 256){
      int dx = i / DIAM - RAD, dy = i % DIAM - RAD;
      int r2 = dx*dx + dy*dy;
      swt_g[i] = (r2 <= RAD*RAD) ? (float)exp(-0.5 * (double)r2 / 225.0) : 0.0f;
    }
  }
}

// ---------------- bilateral: R7-PASSED version (verbatim) ----------------
// 256 thr, u8 tile stride 68, register-cached u32 rows, 32x bank-replicated wc.
__global__ __launch_bounds__(256) void k_bilateral(const u8* __restrict__ q, u8* __restrict__ filt,
                                                   const float* __restrict__ wc_g,
                                                   const float* __restrict__ swt_g){
  __shared__ __align__(16) u8 sm[32768 + 62*68];
  float* wcr  = (float*)sm;                 // [256][32] replicated
  u8*   tileB = sm + 32768;                 // [62][68] halo tile (stride 68)
  int b = blockIdx.z;
  int gx0 = blockIdx.x * 32, gy0 = blockIdx.y * 32;
  int tid = threadIdx.x;
  const u8* qb = q + ((size_t)b << 16);
  {
    float v = wc_g[tid];
    float4 v4 = make_float4(v, v, v, v);
    #pragma unroll
    for (int k = 0; k < 8; ++k) *(float4*)&wcr[tid*32 + k*4] = v4;
  }
  for (int i = tid; i < 62*62; i += 256){
    int ly = i / 62, lx = i % 62;
    int gy = gy0 + ly - RAD, gx = gx0 + lx - RAD;
    gy = gy < 0 ? -gy : (gy > 255 ? 510 - gy : gy);   // jnp.pad reflect
    gx = gx < 0 ? -gx : (gx > 255 ? 510 - gx : gx);
    tileB[ly*68 + lx] = qb[(gy << 8) + gx];
  }
  __syncthreads();
  int tx8 = tid & 7, r = tid >> 3;          // 8 col-groups x 32 rows
  int lk = (tid & 31);
  int cbase = (r + RAD)*68 + RAD + 4*tx8;
  float c_f[4], num[4], den[4];
  #pragma unroll
  for (int p = 0; p < 4; ++p){
    c_f[p] = (float)tileB[cbase + p];
    num[p] = 0.f; den[p] = 0.f;
  }
  #pragma unroll 1
  for (int dx = -RAD; dx <= RAD; ++dx){
    int dxx = dx*dx;
    int rowoff = (r + dx + RAD)*68 + 4*tx8;
    unsigned wrow[9];
    #pragma unroll
    for (int k = 0; k < 9; ++k) wrow[k] = *(const unsigned*)(tileB + rowoff + 4*k);
    const float* swrow = swt_g + (dx + RAD)*DIAM + RAD;
    #pragma unroll
    for (int DY = -RAD; DY <= RAD; ++DY){
      if (dxx + DY*DY <= RAD*RAD){
        float sw = swrow[DY];               // wave-uniform -> scalar load
        #pragma unroll
        for (int p = 0; p < 4; ++p){
          const int B = RAD + p + DY;       // 0..33, compile-time
          float shf = (float)((wrow[B >> 2] >> ((B & 3)*8)) & 255u);
          float diff = __fsub_rn(shf, c_f[p]);
          int idx = (int)fabsf(diff);
          float wcd = wcr[(idx << 5) + lk]; // conflict-free gather
          float w = __fmul_rn(sw, wcd);
          num[p] = __fadd_rn(num[p], __fmul_rn(w, shf));
          den[p] = __fadd_rn(den[p], w);
        }
      }
    }
  }
  unsigned pack = 0;
  #pragma unroll
  for (int p = 0; p < 4; ++p)
    pack |= ((unsigned)(int)rintf(__fdiv_rn(num[p], den[p]))) << (p*8);
  int gy = gy0 + r, gx = gx0 + 4*tx8;
  *(unsigned*)(filt + ((size_t)b << 16) + (gy << 8) + gx) = pack;
}

// ---------------- LBP ----------------
__global__ __launch_bounds__(256) void k_lbp(const u8* __restrict__ filt, u8* __restrict__ lbp){
  int i = blockIdx.x*256 + threadIdx.x;
  int b = i >> 16, p = i & 65535, y = p >> 8, x = p & 255;
  int v = 0;
  if (y > 0 && y < 255 && x > 0 && x < 255){
    const u8* f = filt + ((size_t)b << 16);
    int c = f[(y << 8) + x];
    int pat = 128;
    pat += (f[((y+1) << 8) + x]     >= c) ? 1  : 0;
    pat += (f[(y << 8) + x - 1]     >= c) ? 6  : 0;
    pat += (f[((y-1) << 8) + x - 1] >= c) ? 8  : 0;
    pat += (f[((y-1) << 8) + x]     >= c) ? 48 : 0;
    pat += (f[(y << 8) + x + 1]     >= c) ? 64 : 0;
    v = pat;
  }
  lbp[i] = (u8)v;
}

// ---------------- per-block channel stats (conv1 pass) ----------------
template<int OC>
__device__ __forceinline__ void block_stats(const float* acc, float* red, int tid, float* out){
  #pragma unroll
  for (int c0 = 0; c0 < OC; c0 += 8){
    #pragma unroll
    for (int pass = 0; pass < 2; ++pass){
      __syncthreads();
      #pragma unroll
      for (int j = 0; j < 8; ++j){
        float v = acc[c0 + j];
        red[tid*8 + j] = pass ? __fmul_rn(v, v) : v;
      }
      __syncthreads();
      int i = tid >> 5, s = tid & 31;
      float v = 0.f;
      #pragma unroll
      for (int k = 0; k < 8; ++k) v += red[(s + 32*k)*8 + i];
      v += __shfl_xor(v, 1); v += __shfl_xor(v, 2); v += __shfl_xor(v, 4);
      v += __shfl_xor(v, 8); v += __shfl_xor(v, 16);
      if (s == 0) out[2*(c0 + i) + pass] = v;
    }
  }
}

// ---------------- pass A: conv1 stats only ----------------
__global__ __launch_bounds__(256) void k_stats1(const u8* __restrict__ lbp, const float* __restrict__ w1,
                                                float* __restrict__ part1){
  __shared__ float t[18][18];
  __shared__ float wl[288];
  __shared__ float red[2048];
  int b = blockIdx.z;
  int ty0 = blockIdx.y * 16, tx0 = blockIdx.x * 16;
  int tid = threadIdx.x, tx = tid & 15, ty = tid >> 4;
  for (int i = tid; i < 288; i += 256) wl[i] = w1[i];
  for (int i = tid; i < 324; i += 256){
    int iy = i / 18, ix = i % 18;
    int gy = ty0 + iy - 1, gx = tx0 + ix - 1;
    float v = 0.f;
    if ((unsigned)gy < 256u && (unsigned)gx < 256u)
      v = __fdiv_rn((float)lbp[((size_t)b << 16) + (gy << 8) + gx], 255.0f);
    t[iy][ix] = v;
  }
  __syncthreads();
  float v[9];
  #pragma unroll
  for (int j = 0; j < 9; ++j) v[j] = t[ty + j/3][tx + j%3];
  float acc[32];
  #pragma unroll
  for (int oc = 0; oc < 32; ++oc){
    float a = 0.f;
    #pragma unroll
    for (int j = 0; j < 9; ++j) a = fmaf(v[j], wl[oc*9 + j], a);
    acc[oc] = a;
  }
  int blk = (blockIdx.z * 16 + blockIdx.y) * 16 + blockIdx.x;
  block_stats<32>(acc, red, tid, part1 + (size_t)blk * 64);
}

// ---------------- finalize BN stats ----------------
__global__ __launch_bounds__(256) void k_stats(const float* __restrict__ part, int stride, int OC,
                                               const float* __restrict__ g, const float* __restrict__ beta,
                                               float* __restrict__ st){
  int ch = blockIdx.x, tid = threadIdx.x;
  double s = 0.0, s2 = 0.0;
  for (int k = tid; k < 2048; k += 256){
    const float* pp = part + (size_t)k * stride + 2*ch;
    s += (double)pp[0]; s2 += (double)pp[1];
  }
  #pragma unroll
  for (int m = 1; m <= 32; m <<= 1){ s += __shfl_xor(s, m); s2 += __shfl_xor(s2, m); }
  __shared__ double red[8];
  if ((tid & 63) == 0){ red[(tid >> 6)*2] = s; red[(tid >> 6)*2 + 1] = s2; }
  __syncthreads();
  if (tid == 0){
    s  = red[0] + red[2] + red[4] + red[6];
    s2 = red[1] + red[3] + red[5] + red[7];
    double mean = s / 524288.0;
    double var  = s2 / 524288.0 - mean*mean;
    double rs   = 1.0 / sqrt(var + 1e-5);
    double sc   = (double)g[ch] * rs;
    st[ch]      = (float)sc;
    st[OC + ch] = (float)((double)beta[ch] - mean * sc);
  }
}

// ---------------- fused conv1+bn1+relu+conv2 (bf16 MFMA), stats2 + RAW pooled out ----------------
// Pool-before-bn2 exact: sc2 = g2*rsqrt(var)>0 (g2==1); fmaf monotone => max commutes bitwise.
#define SM_Y1   0                       // ushort[324][40] = 25920 B
#define SM_LT   25920                   // float[400] = 1600 B
#define SM_WL   27520                   // float[288] = 1152 B
#define SM_RED  25920                   // float[512] alias (lt/wl dead post-conv1)
__global__ __launch_bounds__(256) void k_fused(const u8* __restrict__ lbp, const float* __restrict__ w1,
                                               const ushort_t* __restrict__ w2b,
                                               const float* __restrict__ st1,
                                               float* __restrict__ part2, float* __restrict__ out){
  __shared__ __align__(16) u8 smem[28672];
  ushort_t* y1h = (ushort_t*)(smem + SM_Y1);
  float*    lt  = (float*)(smem + SM_LT);
  float*    wl  = (float*)(smem + SM_WL);
  int b = blockIdx.z;
  int ty0 = blockIdx.y * 16, tx0 = blockIdx.x * 16;
  int tid = threadIdx.x;
  for (int i = tid; i < 288; i += 256) wl[i] = w1[i];
  for (int i = tid; i < 400; i += 256){
    int iy = i / 20, ix = i % 20;
    int gy = ty0 + iy - 2, gx = tx0 + ix - 2;
    float v = 0.f;
    if ((unsigned)gy < 256u && (unsigned)gx < 256u)
      v = __fdiv_rn((float)lbp[((size_t)b << 16) + (gy << 8) + gx], 255.0f);
    lt[i] = v;
  }
  __syncthreads();
  for (int i = tid; i < 324; i += 256){
    int jy = i / 18, jx = i % 18;
    int gy = ty0 + jy - 1, gx = tx0 + jx - 1;
    bool in = ((unsigned)gy < 256u) && ((unsigned)gx < 256u);
    float v[9];
    #pragma unroll
    for (int j = 0; j < 9; ++j) v[j] = lt[(jy + j/3)*20 + jx + j%3];
    ushort_t* row = y1h + i*40;
    #pragma unroll
    for (int o4 = 0; o4 < 4; ++o4){
      unsigned tmp[4];
      #pragma unroll
      for (int j2 = 0; j2 < 4; ++j2){
        int oc = o4*8 + j2*2;
        float a0 = 0.f, a1 = 0.f;
        #pragma unroll
        for (int j = 0; j < 9; ++j){
          a0 = fmaf(v[j], wl[(oc  )*9 + j], a0);
          a1 = fmaf(v[j], wl[(oc+1)*9 + j], a1);
        }
        float r0 = in ? fmaxf(fmaf(a0, st1[oc  ], st1[32 + oc  ]), 0.f) : 0.f;
        float r1 = in ? fmaxf(fmaf(a1, st1[oc+1], st1[32 + oc+1]), 0.f) : 0.f;
        tmp[j2] = (unsigned)f2bf(r0) | ((unsigned)f2bf(r1) << 16);
      }
      *(uint4*)(row + o4*8) = make_uint4(tmp[0], tmp[1], tmp[2], tmp[3]);
    }
  }
  __syncthreads();
  int lane = tid & 63, w = tid >> 6;
  int mA = lane & 15, g = lane >> 4;
  int pyA = mA >> 2, pxA = mA & 3;
  f32x4 acc[4][4] = {};
  #pragma unroll 3
  for (int t = 0; t < 9; ++t){
    int dy = t/3, dx = t%3;
    bf16x8 bf[4];
    #pragma unroll
    for (int o = 0; o < 4; ++o) bf[o] = *(const bf16x8*)(w2b + (((t*4 + o) << 6) + lane)*8);
    #pragma unroll
    for (int i = 0; i < 4; ++i){
      int jy = (w << 2) + pyA + dy, jx = (i << 2) + pxA + dx;
      bf16x8 a = *(const bf16x8*)(y1h + (jy*18 + jx)*40 + g*8);
      #pragma unroll
      for (int o = 0; o < 4; ++o)
        acc[i][o] = __builtin_amdgcn_mfma_f32_16x16x32_bf16(a, bf[o], acc[i][o], 0, 0, 0);
    }
  }
  int col = lane & 15;
  // ---- stats2 partials ----
  {
    float* red = (float*)(smem + SM_RED);
    float s[4], s2[4];
    #pragma unroll
    for (int o = 0; o < 4; ++o){
      s[o] = 0.f; s2[o] = 0.f;
      #pragma unroll
      for (int i = 0; i < 4; ++i)
        #pragma unroll
        for (int rr = 0; rr < 4; ++rr){
          float v = acc[i][o][rr];
          s[o] += v; s2[o] = fmaf(v, v, s2[o]);
        }
      s[o]  += __shfl_xor(s[o], 16);  s[o]  += __shfl_xor(s[o], 32);
      s2[o] += __shfl_xor(s2[o], 16); s2[o] += __shfl_xor(s2[o], 32);
    }
    if (g == 0){
      #pragma unroll
      for (int o = 0; o < 4; ++o){
        red[((0*4 + w)*4 + o)*16 + col] = s[o];
        red[((1*4 + w)*4 + o)*16 + col] = s2[o];
      }
    }
    __syncthreads();
    if (tid < 128){
      int stat = tid >> 6, oc = tid & 63, o = oc >> 4, c = oc & 15;
      float* red2 = (float*)(smem + SM_RED);
      float sum = 0.f;
      #pragma unroll
      for (int ww = 0; ww < 4; ++ww) sum += red2[((stat*4 + ww)*4 + o)*16 + c];
      int blk = (blockIdx.z * 16 + blockIdx.y) * 16 + blockIdx.x;
      part2[(size_t)blk * 128 + 2*oc + stat] = sum;
    }
  }
  // ---- raw 2x2 maxpool -> out ----
  {
    float* pool = (float*)(smem + SM_Y1);      // [64][66] padded (aliases y1h, reads done)
    #pragma unroll
    for (int o = 0; o < 4; ++o){
      int oc = (o << 4) + col;
      #pragma unroll
      for (int i = 0; i < 4; ++i){
        float h0 = fmaxf(acc[i][o][0], acc[i][o][1]);
        float h2 = fmaxf(acc[i][o][2], acc[i][o][3]);
        float p0 = fmaxf(h0, __shfl_xor(h0, 16));
        float p2 = fmaxf(h2, __shfl_xor(h2, 16));
        if (!(g & 1)){
          *(float2*)&pool[oc*66 + (w*2 + (g >> 1))*8 + i*2] = make_float2(p0, p2);
        }
      }
    }
    __syncthreads();
    int Y0 = blockIdx.y * 8, X0 = blockIdx.x * 8;
    for (int k = tid; k < 1024; k += 256){
      int oc = k >> 4, quad = k & 15;
      int row = quad >> 1, c4 = (quad & 1) * 4;
      float4 v = *(float4*)&pool[oc*66 + quad*4];
      *(float4*)&out[(((size_t)b*64 + oc) << 14) + (size_t)(Y0 + row)*128 + X0 + c4] = v;
    }
  }
}

// ---------------- bn2 + relu, in-place on pooled out ----------------
__global__ __launch_bounds__(256) void k_bn2(float* __restrict__ out, const float* __restrict__ st2){
  int i = blockIdx.x*256 + threadIdx.x;       // 2097152 float4
  int oc = (i >> 12) & 63;
  float sc = st2[oc], sh = st2[64 + oc];
  float4 v = ((float4*)out)[i];
  v.x = fmaxf(fmaf(v.x, sc, sh), 0.f);
  v.y = fmaxf(fmaf(v.y, sc, sh), 0.f);
  v.z = fmaxf(fmaf(v.z, sc, sh), 0.f);
  v.w = fmaxf(fmaf(v.w, sc, sh), 0.f);
  ((float4*)out)[i] = v;
}

extern "C" void kernel_launch(void* const* d_in, const int* in_sizes, int n_in,
                              void* d_out, int out_size, void* d_ws, size_t ws_size,
                              hipStream_t stream){
  const float* img = (const float*)d_in[0];
  const float* w1  = (const float*)d_in[1];
  const float* g1  = (const float*)d_in[3];
  const float* be1 = (const float*)d_in[4];
  const float* w2  = (const float*)d_in[5];
  const float* g2  = (const float*)d_in[7];
  const float* be2 = (const float*)d_in[8];
  float* out = (float*)d_out;

  char* base = (char*)d_ws;                       // ~3.2 MB total
  u8*       q    = (u8*)(base + 0);
  u8*       filt = (u8*)(base + 524288);
  u8*       lbp  = (u8*)(base + 1048576);
  ushort_t* w2b  = (ushort_t*)(base + 1572864);   // 36864
  float*    wc_g = (float*)(base + 1609728);      // 1024
  float*    swtg = (float*)(base + 1610752);      // 3856
  float*    p1   = (float*)(base + 1614608);      // 524288
  float*    p2   = (float*)(base + 2138896);      // 1048576
  float*    st1  = (float*)(base + 3187472);      // 256
  float*    st2  = (float*)(base + 3187728);      // 512

  k_gray     <<<2048, 256, 0, stream>>>(img, q);
  k_prep     <<<73, 256, 0, stream>>>(w2, w2b, wc_g, swtg);
  k_bilateral<<<dim3(8,8,8), 256, 0, stream>>>(q, filt, wc_g, swtg);
  k_lbp      <<<2048, 256, 0, stream>>>(filt, lbp);
  k_stats1   <<<dim3(16,16,8), 256, 0, stream>>>(lbp, w1, p1);
  k_stats    <<<32, 256, 0, stream>>>(p1, 64, 32, g1, be1, st1);
  k_fused    <<<dim3(16,16,8), 256, 0, stream>>>(lbp, w1, w2b, st1, p2, out);
  k_stats    <<<64, 256, 0, stream>>>(p2, 128, 64, g2, be2, st2);
  k_bn2      <<<8192, 256, 0, stream>>>(out, st2);
}

// Round 12
// 203.899 us; speedup vs baseline: 6.7568x; 1.0137x over previous
//
#include <hip/hip_runtime.h>
#include <math.h>

#define RAD 15
#define DIAM 31

typedef unsigned char u8;
typedef unsigned short ushort_t;
typedef __attribute__((ext_vector_type(8))) short bf16x8;
typedef __attribute__((ext_vector_type(4))) float f32x4;

__device__ __forceinline__ unsigned short f2bf(float f){
  unsigned u = __float_as_uint(f);
  return (unsigned short)((u + 0x7FFFu + ((u >> 16) & 1u)) >> 16);
}

// ---------------- merged: gray+quantize | w2 frags | exp tables ----------------
__global__ __launch_bounds__(256) void k_gp(const float* __restrict__ img, u8* __restrict__ q,
                                            const float* __restrict__ w2, ushort_t* __restrict__ w2b,
                                            float* __restrict__ wc_g, float* __restrict__ swt_g){
  int blk = blockIdx.x, tid = threadIdx.x;
  if (blk < 2048){
    int i = blk*256 + tid;
    int b = i >> 16, p = i & 65535;
    const float* pb = img + (((size_t)b*3) << 16);
    float r = pb[p], g = pb[65536 + p], bl = pb[131072 + p];
    float gray = __fadd_rn(__fadd_rn(__fmul_rn(0.299f, r), __fmul_rn(0.587f, g)), __fmul_rn(0.116f, bl));
    float t = floorf(__fmul_rn(gray, 255.0f));
    t = fminf(fmaxf(t, 0.0f), 255.0f);
    q[i] = (u8)(int)t;
  } else if (blk < 2120){
    int i = (blk - 2048)*256 + tid;     // 72*256 = 18432
    int j = i & 7, l = (i >> 3) & 63, fo = i >> 9;
    int t = fo >> 2, o = fo & 3;
    int oc = o*16 + (l & 15), ic = (l >> 4)*8 + j;
    w2b[i] = f2bf(w2[(oc*32 + ic)*9 + t]);
  } else {
    const float inv2sc2 = (float)(-0.5/5625.0);
    float df = (float)tid;
    float t = __fmul_rn(__fmul_rn(inv2sc2, df), df);
    wc_g[tid] = (float)exp((double)t);                 // correctly-rounded f32 exp
    for (int i = tid; i < DIAM*DIAM; i += 256){
      int dx = i / DIAM - RAD, dy = i % DIAM - RAD;
      int r2 = dx*dx + dy*dy;
      swt_g[i] = (r2 <= RAD*RAD) ? (float)exp(-0.5 * (double)r2 / 225.0) : 0.0f;
    }
  }
}

// ---------------- bilateral: R9-PASSED version (verbatim) ----------------
__global__ __launch_bounds__(256) void k_bilateral(const u8* __restrict__ q, u8* __restrict__ filt,
                                                   const float* __restrict__ wc_g,
                                                   const float* __restrict__ swt_g){
  __shared__ __align__(16) u8 sm[32768 + 62*68];
  float* wcr  = (float*)sm;                 // [256][32] replicated
  u8*   tileB = sm + 32768;                 // [62][68] halo tile (stride 68)
  int b = blockIdx.z;
  int gx0 = blockIdx.x * 32, gy0 = blockIdx.y * 32;
  int tid = threadIdx.x;
  const u8* qb = q + ((size_t)b << 16);
  {
    float v = wc_g[tid];
    float4 v4 = make_float4(v, v, v, v);
    #pragma unroll
    for (int k = 0; k < 8; ++k) *(float4*)&wcr[tid*32 + k*4] = v4;
  }
  for (int i = tid; i < 62*62; i += 256){
    int ly = i / 62, lx = i % 62;
    int gy = gy0 + ly - RAD, gx = gx0 + lx - RAD;
    gy = gy < 0 ? -gy : (gy > 255 ? 510 - gy : gy);   // jnp.pad reflect
    gx = gx < 0 ? -gx : (gx > 255 ? 510 - gx : gx);
    tileB[ly*68 + lx] = qb[(gy << 8) + gx];
  }
  __syncthreads();
  int tx8 = tid & 7, r = tid >> 3;          // 8 col-groups x 32 rows
  int lk = (tid & 31);
  int cbase = (r + RAD)*68 + RAD + 4*tx8;
  float c_f[4], num[4], den[4];
  #pragma unroll
  for (int p = 0; p < 4; ++p){
    c_f[p] = (float)tileB[cbase + p];
    num[p] = 0.f; den[p] = 0.f;
  }
  #pragma unroll 1
  for (int dx = -RAD; dx <= RAD; ++dx){
    int dxx = dx*dx;
    int rowoff = (r + dx + RAD)*68 + 4*tx8;
    unsigned wrow[9];
    #pragma unroll
    for (int k = 0; k < 9; ++k) wrow[k] = *(const unsigned*)(tileB + rowoff + 4*k);
    const float* swrow = swt_g + (dx + RAD)*DIAM + RAD;
    #pragma unroll
    for (int DY = -RAD; DY <= RAD; ++DY){
      if (dxx + DY*DY <= RAD*RAD){
        float sw = swrow[DY];               // wave-uniform -> scalar load
        #pragma unroll
        for (int p = 0; p < 4; ++p){
          const int B = RAD + p + DY;       // 0..33, compile-time
          float shf = (float)((wrow[B >> 2] >> ((B & 3)*8)) & 255u);
          float diff = __fsub_rn(shf, c_f[p]);
          int idx = (int)fabsf(diff);
          float wcd = wcr[(idx << 5) + lk]; // conflict-free gather
          float w = __fmul_rn(sw, wcd);
          num[p] = __fadd_rn(num[p], __fmul_rn(w, shf));
          den[p] = __fadd_rn(den[p], w);
        }
      }
    }
  }
  unsigned pack = 0;
  #pragma unroll
  for (int p = 0; p < 4; ++p)
    pack |= ((unsigned)(int)rintf(__fdiv_rn(num[p], den[p]))) << (p*8);
  int gy = gy0 + r, gx = gx0 + 4*tx8;
  *(unsigned*)(filt + ((size_t)b << 16) + (gy << 8) + gx) = pack;
}

// ---------------- per-block channel stats ----------------
template<int OC>
__device__ __forceinline__ void block_stats(const float* acc, float* red, int tid, float* out){
  #pragma unroll
  for (int c0 = 0; c0 < OC; c0 += 8){
    #pragma unroll
    for (int pass = 0; pass < 2; ++pass){
      __syncthreads();
      #pragma unroll
      for (int j = 0; j < 8; ++j){
        float v = acc[c0 + j];
        red[tid*8 + j] = pass ? __fmul_rn(v, v) : v;
      }
      __syncthreads();
      int i = tid >> 5, s = tid & 31;
      float v = 0.f;
      #pragma unroll
      for (int k = 0; k < 8; ++k) v += red[(s + 32*k)*8 + i];
      v += __shfl_xor(v, 1); v += __shfl_xor(v, 2); v += __shfl_xor(v, 4);
      v += __shfl_xor(v, 8); v += __shfl_xor(v, 16);
      if (s == 0) out[2*(c0 + i) + pass] = v;
    }
  }
}

// ---------------- fused LBP + conv1-stats: filt -> lbp (global) + part1 ----------------
// Same 16x16 tile/grid and thread->pixel map as the old k_stats1 => st1 bit-identical.
__global__ __launch_bounds__(256) void k_lbp1(const u8* __restrict__ filt, const float* __restrict__ w1,
                                              u8* __restrict__ lbp, float* __restrict__ part1){
  __shared__ u8    ft[20][20];
  __shared__ float lt[18][18];
  __shared__ float wl[288];
  __shared__ float red[2048];
  int b = blockIdx.z;
  int ty0 = blockIdx.y * 16, tx0 = blockIdx.x * 16;
  int tid = threadIdx.x, tx = tid & 15, ty = tid >> 4;
  for (int i = tid; i < 288; i += 256) wl[i] = w1[i];
  for (int i = tid; i < 400; i += 256){
    int iy = i / 20, ix = i % 20;
    int gy = ty0 + iy - 2, gx = tx0 + ix - 2;
    u8 v = 0;
    if ((unsigned)gy < 256u && (unsigned)gx < 256u) v = filt[((size_t)b << 16) + (gy << 8) + gx];
    ft[iy][ix] = v;
  }
  __syncthreads();
  for (int i = tid; i < 324; i += 256){
    int jy = i / 18, jx = i % 18;           // lbp pixel (ty0+jy-1, tx0+jx-1) = ft[jy+1][jx+1]
    int gy = ty0 + jy - 1, gx = tx0 + jx - 1;
    int pat = 0;
    if (gy > 0 && gy < 255 && gx > 0 && gx < 255){
      int c = ft[jy+1][jx+1];
      pat = 128;
      pat += (ft[jy+2][jx+1] >= c) ? 1  : 0;   // (+1, 0)
      pat += (ft[jy+1][jx  ] >= c) ? 6  : 0;   // ( 0,-1)
      pat += (ft[jy  ][jx  ] >= c) ? 8  : 0;   // (-1,-1)
      pat += (ft[jy  ][jx+1] >= c) ? 48 : 0;   // (-1, 0)
      pat += (ft[jy+1][jx+2] >= c) ? 64 : 0;   // ( 0,+1)
    }
    lt[jy][jx] = __fdiv_rn((float)pat, 255.0f);
    if (jy >= 1 && jy <= 16 && jx >= 1 && jx <= 16 && (unsigned)gy < 256u && (unsigned)gx < 256u)
      lbp[((size_t)b << 16) + (gy << 8) + gx] = (u8)pat;
  }
  __syncthreads();
  float v[9];
  #pragma unroll
  for (int j = 0; j < 9; ++j) v[j] = lt[ty + j/3][tx + j%3];
  float acc[32];
  #pragma unroll
  for (int oc = 0; oc < 32; ++oc){
    float a = 0.f;
    #pragma unroll
    for (int j = 0; j < 9; ++j) a = fmaf(v[j], wl[oc*9 + j], a);
    acc[oc] = a;
  }
  int blk = (blockIdx.z * 16 + blockIdx.y) * 16 + blockIdx.x;
  block_stats<32>(acc, red, tid, part1 + (size_t)blk * 64);
}

// ---------------- finalize BN stats ----------------
__global__ __launch_bounds__(256) void k_stats(const float* __restrict__ part, int stride, int OC,
                                               const float* __restrict__ g, const float* __restrict__ beta,
                                               float* __restrict__ st){
  int ch = blockIdx.x, tid = threadIdx.x;
  double s = 0.0, s2 = 0.0;
  for (int k = tid; k < 2048; k += 256){
    const float* pp = part + (size_t)k * stride + 2*ch;
    s += (double)pp[0]; s2 += (double)pp[1];
  }
  #pragma unroll
  for (int m = 1; m <= 32; m <<= 1){ s += __shfl_xor(s, m); s2 += __shfl_xor(s2, m); }
  __shared__ double red[8];
  if ((tid & 63) == 0){ red[(tid >> 6)*2] = s; red[(tid >> 6)*2 + 1] = s2; }
  __syncthreads();
  if (tid == 0){
    s  = red[0] + red[2] + red[4] + red[6];
    s2 = red[1] + red[3] + red[5] + red[7];
    double mean = s / 524288.0;
    double var  = s2 / 524288.0 - mean*mean;
    double rs   = 1.0 / sqrt(var + 1e-5);
    double sc   = (double)g[ch] * rs;
    st[ch]      = (float)sc;
    st[OC + ch] = (float)((double)beta[ch] - mean * sc);
  }
}

// ---------------- fused conv1+bn1+relu+conv2 (bf16 MFMA), stats2 + RAW pooled out ----------------
// Pool-before-bn2 exact: sc2 = g2*rsqrt(var)>0 (g2==1); fmaf monotone => max commutes bitwise.
#define SM_Y1   0                       // ushort[324][40] = 25920 B
#define SM_LT   25920                   // float[400] = 1600 B
#define SM_WL   27520                   // float[288] = 1152 B
#define SM_RED  25920                   // float[512] alias (lt/wl dead post-conv1)
__global__ __launch_bounds__(256) void k_fused(const u8* __restrict__ lbp, const float* __restrict__ w1,
                                               const ushort_t* __restrict__ w2b,
                                               const float* __restrict__ st1,
                                               float* __restrict__ part2, float* __restrict__ out){
  __shared__ __align__(16) u8 smem[28672];
  ushort_t* y1h = (ushort_t*)(smem + SM_Y1);
  float*    lt  = (float*)(smem + SM_LT);
  float*    wl  = (float*)(smem + SM_WL);
  int b = blockIdx.z;
  int ty0 = blockIdx.y * 16, tx0 = blockIdx.x * 16;
  int tid = threadIdx.x;
  for (int i = tid; i < 288; i += 256) wl[i] = w1[i];
  for (int i = tid; i < 400; i += 256){
    int iy = i / 20, ix = i % 20;
    int gy = ty0 + iy - 2, gx = tx0 + ix - 2;
    float v = 0.f;
    if ((unsigned)gy < 256u && (unsigned)gx < 256u)
      v = __fdiv_rn((float)lbp[((size_t)b << 16) + (gy << 8) + gx], 255.0f);
    lt[i] = v;
  }
  __syncthreads();
  for (int i = tid; i < 324; i += 256){
    int jy = i / 18, jx = i % 18;
    int gy = ty0 + jy - 1, gx = tx0 + jx - 1;
    bool in = ((unsigned)gy < 256u) && ((unsigned)gx < 256u);
    float v[9];
    #pragma unroll
    for (int j = 0; j < 9; ++j) v[j] = lt[(jy + j/3)*20 + jx + j%3];
    ushort_t* row = y1h + i*40;
    #pragma unroll
    for (int o4 = 0; o4 < 4; ++o4){
      unsigned tmp[4];
      #pragma unroll
      for (int j2 = 0; j2 < 4; ++j2){
        int oc = o4*8 + j2*2;
        float a0 = 0.f, a1 = 0.f;
        #pragma unroll
        for (int j = 0; j < 9; ++j){
          a0 = fmaf(v[j], wl[(oc  )*9 + j], a0);
          a1 = fmaf(v[j], wl[(oc+1)*9 + j], a1);
        }
        float r0 = in ? fmaxf(fmaf(a0, st1[oc  ], st1[32 + oc  ]), 0.f) : 0.f;
        float r1 = in ? fmaxf(fmaf(a1, st1[oc+1], st1[32 + oc+1]), 0.f) : 0.f;
        tmp[j2] = (unsigned)f2bf(r0) | ((unsigned)f2bf(r1) << 16);
      }
      *(uint4*)(row + o4*8) = make_uint4(tmp[0], tmp[1], tmp[2], tmp[3]);
    }
  }
  __syncthreads();
  int lane = tid & 63, w = tid >> 6;
  int mA = lane & 15, g = lane >> 4;
  int pyA = mA >> 2, pxA = mA & 3;
  f32x4 acc[4][4] = {};
  #pragma unroll 3
  for (int t = 0; t < 9; ++t){
    int dy = t/3, dx = t%3;
    bf16x8 bf[4];
    #pragma unroll
    for (int o = 0; o < 4; ++o) bf[o] = *(const bf16x8*)(w2b + (((t*4 + o) << 6) + lane)*8);
    #pragma unroll
    for (int i = 0; i < 4; ++i){
      int jy = (w << 2) + pyA + dy, jx = (i << 2) + pxA + dx;
      bf16x8 a = *(const bf16x8*)(y1h + (jy*18 + jx)*40 + g*8);
      #pragma unroll
      for (int o = 0; o < 4; ++o)
        acc[i][o] = __builtin_amdgcn_mfma_f32_16x16x32_bf16(a, bf[o], acc[i][o], 0, 0, 0);
    }
  }
  int col = lane & 15;
  // ---- stats2 partials ----
  {
    float* red = (float*)(smem + SM_RED);
    float s[4], s2[4];
    #pragma unroll
    for (int o = 0; o < 4; ++o){
      s[o] = 0.f; s2[o] = 0.f;
      #pragma unroll
      for (int i = 0; i < 4; ++i)
        #pragma unroll
        for (int rr = 0; rr < 4; ++rr){
          float v = acc[i][o][rr];
          s[o] += v; s2[o] = fmaf(v, v, s2[o]);
        }
      s[o]  += __shfl_xor(s[o], 16);  s[o]  += __shfl_xor(s[o], 32);
      s2[o] += __shfl_xor(s2[o], 16); s2[o] += __shfl_xor(s2[o], 32);
    }
    if (g == 0){
      #pragma unroll
      for (int o = 0; o < 4; ++o){
        red[((0*4 + w)*4 + o)*16 + col] = s[o];
        red[((1*4 + w)*4 + o)*16 + col] = s2[o];
      }
    }
    __syncthreads();
    if (tid < 128){
      int stat = tid >> 6, oc = tid & 63, o = oc >> 4, c = oc & 15;
      float* red2 = (float*)(smem + SM_RED);
      float sum = 0.f;
      #pragma unroll
      for (int ww = 0; ww < 4; ++ww) sum += red2[((stat*4 + ww)*4 + o)*16 + c];
      int blk = (blockIdx.z * 16 + blockIdx.y) * 16 + blockIdx.x;
      part2[(size_t)blk * 128 + 2*oc + stat] = sum;
    }
  }
  // ---- raw 2x2 maxpool -> out ----
  {
    float* pool = (float*)(smem + SM_Y1);      // [64][66] padded (aliases y1h, reads done)
    #pragma unroll
    for (int o = 0; o < 4; ++o){
      int oc = (o << 4) + col;
      #pragma unroll
      for (int i = 0; i < 4; ++i){
        float h0 = fmaxf(acc[i][o][0], acc[i][o][1]);
        float h2 = fmaxf(acc[i][o][2], acc[i][o][3]);
        float p0 = fmaxf(h0, __shfl_xor(h0, 16));
        float p2 = fmaxf(h2, __shfl_xor(h2, 16));
        if (!(g & 1)){
          *(float2*)&pool[oc*66 + (w*2 + (g >> 1))*8 + i*2] = make_float2(p0, p2);
        }
      }
    }
    __syncthreads();
    int Y0 = blockIdx.y * 8, X0 = blockIdx.x * 8;
    for (int k = tid; k < 1024; k += 256){
      int oc = k >> 4, quad = k & 15;
      int row = quad >> 1, c4 = (quad & 1) * 4;
      float4 v = *(float4*)&pool[oc*66 + quad*4];
      *(float4*)&out[(((size_t)b*64 + oc) << 14) + (size_t)(Y0 + row)*128 + X0 + c4] = v;
    }
  }
}

// ---------------- bn2 + relu, in-place on pooled out ----------------
__global__ __launch_bounds__(256) void k_bn2(float* __restrict__ out, const float* __restrict__ st2){
  int i = blockIdx.x*256 + threadIdx.x;       // 2097152 float4
  int oc = (i >> 12) & 63;
  float sc = st2[oc], sh = st2[64 + oc];
  float4 v = ((float4*)out)[i];
  v.x = fmaxf(fmaf(v.x, sc, sh), 0.f);
  v.y = fmaxf(fmaf(v.y, sc, sh), 0.f);
  v.z = fmaxf(fmaf(v.z, sc, sh), 0.f);
  v.w = fmaxf(fmaf(v.w, sc, sh), 0.f);
  ((float4*)out)[i] = v;
}

extern "C" void kernel_launch(void* const* d_in, const int* in_sizes, int n_in,
                              void* d_out, int out_size, void* d_ws, size_t ws_size,
                              hipStream_t stream){
  const float* img = (const float*)d_in[0];
  const float* w1  = (const float*)d_in[1];
  const float* g1  = (const float*)d_in[3];
  const float* be1 = (const float*)d_in[4];
  const float* w2  = (const float*)d_in[5];
  const float* g2  = (const float*)d_in[7];
  const float* be2 = (const float*)d_in[8];
  float* out = (float*)d_out;

  char* base = (char*)d_ws;                       // ~3.2 MB total
  u8*       q    = (u8*)(base + 0);
  u8*       filt = (u8*)(base + 524288);
  u8*       lbp  = (u8*)(base + 1048576);
  ushort_t* w2b  = (ushort_t*)(base + 1572864);   // 36864
  float*    wc_g = (float*)(base + 1609728);      // 1024
  float*    swtg = (float*)(base + 1610752);      // 3856
  float*    p1   = (float*)(base + 1614608);      // 524288
  float*    p2   = (float*)(base + 2138896);      // 1048576
  float*    st1  = (float*)(base + 3187472);      // 256
  float*    st2  = (float*)(base + 3187728);      // 512

  k_gp       <<<2121, 256, 0, stream>>>(img, q, w2, w2b, wc_g, swtg);
  k_bilateral<<<dim3(8,8,8), 256, 0, stream>>>(q, filt, wc_g, swtg);
  k_lbp1     <<<dim3(16,16,8), 256, 0, stream>>>(filt, w1, lbp, p1);
  k_stats    <<<32, 256, 0, stream>>>(p1, 64, 32, g1, be1, st1);
  k_fused    <<<dim3(16,16,8), 256, 0, stream>>>(lbp, w1, w2b, st1, p2, out);
  k_stats    <<<64, 256, 0, stream>>>(p2, 128, 64, g2, be2, st2);
  k_bn2      <<<8192, 256, 0, stream>>>(out, st2);
}

// Round 17
// 196.631 us; speedup vs baseline: 7.0065x; 1.0370x over previous
//
#include <hip/hip_runtime.h>
#include <math.h>

#define RAD 15
#define DIAM 31

typedef unsigned char u8;
typedef unsigned short ushort_t;
typedef __attribute__((ext_vector_type(8))) short bf16x8;
typedef __attribute__((ext_vector_type(4))) float f32x4;

__device__ __forceinline__ unsigned short f2bf(float f){
  unsigned u = __float_as_uint(f);
  return (unsigned short)((u + 0x7FFFu + ((u >> 16) & 1u)) >> 16);
}

// asm-pinned IEEE fp32 ops: compiler cannot contract/reassociate/resequence these.
__device__ __forceinline__ float asub(float a, float b){ float d; asm("v_sub_f32 %0, %1, %2" : "=v"(d) : "v"(a), "v"(b)); return d; }
__device__ __forceinline__ float amul(float a, float b){ float d; asm("v_mul_f32 %0, %1, %2" : "=v"(d) : "v"(a), "v"(b)); return d; }
__device__ __forceinline__ void  aacc(float& acc, float v){ asm("v_add_f32 %0, %0, %1" : "+v"(acc) : "v"(v)); }
// fused num-accumulate: the np/XLA reference evaluates num + w*sh as FMA (R16 proved
// sequential mul+add is WRONG vs ref; passing 4px builds contracted, 2px builds didn't).
__device__ __forceinline__ void  afma(float& acc, float a, float b){ asm("v_fmac_f32 %0, %1, %2" : "+v"(acc) : "v"(a), "v"(b)); }

// ---------------- merged: gray+quantize | w2 frags | exp tables ----------------
__global__ __launch_bounds__(256) void k_gp(const float* __restrict__ img, u8* __restrict__ q,
                                            const float* __restrict__ w2, ushort_t* __restrict__ w2b,
                                            float* __restrict__ wc_g, float* __restrict__ swt_g){
  int blk = blockIdx.x, tid = threadIdx.x;
  if (blk < 2048){
    int i = blk*256 + tid;
    int b = i >> 16, p = i & 65535;
    const float* pb = img + (((size_t)b*3) << 16);
    float r = pb[p], g = pb[65536 + p], bl = pb[131072 + p];
    float gray = __fadd_rn(__fadd_rn(__fmul_rn(0.299f, r), __fmul_rn(0.587f, g)), __fmul_rn(0.116f, bl));
    float t = floorf(__fmul_rn(gray, 255.0f));
    t = fminf(fmaxf(t, 0.0f), 255.0f);
    q[i] = (u8)(int)t;
  } else if (blk < 2120){
    int i = (blk - 2048)*256 + tid;     // 72*256 = 18432
    int j = i & 7, l = (i >> 3) & 63, fo = i >> 9;
    int t = fo >> 2, o = fo & 3;
    int oc = o*16 + (l & 15), ic = (l >> 4)*8 + j;
    w2b[i] = f2bf(w2[(oc*32 + ic)*9 + t]);
  } else {
    const float inv2sc2 = (float)(-0.5/5625.0);
    float df = (float)tid;
    float t = __fmul_rn(__fmul_rn(inv2sc2, df), df);
    wc_g[tid] = (float)exp((double)t);                 // correctly-rounded f32 exp
    for (int i = tid; i < DIAM*DIAM; i += 256){
      int dx = i / DIAM - RAD, dy = i % DIAM - RAD;
      int r2 = dx*dx + dy*dy;
      swt_g[i] = (r2 <= RAD*RAD) ? (float)exp(-0.5 * (double)r2 / 225.0) : 0.0f;
    }
  }
}

// ---------------- bilateral per-pixel-pair body, pinned: num via FMA, den via add ----------------
template<int BASE>
__device__ __forceinline__ void bil_body(const u8* tileB, const float* wcr, const float* swt_g,
                                         int r, int tx8, int lk, float c0, float c1,
                                         float& num0, float& den0, float& num1, float& den1){
  #pragma unroll 1
  for (int dx = -RAD; dx <= RAD; ++dx){
    int dxx = dx*dx;
    int rowoff = (r + dx + RAD)*68 + 4*tx8;
    unsigned wrow[9];
    #pragma unroll
    for (int k = 0; k < 9; ++k) wrow[k] = *(const unsigned*)(tileB + rowoff + 4*k);
    const float* swrow = swt_g + (dx + RAD)*DIAM + RAD;
    #pragma unroll
    for (int DY = -RAD; DY <= RAD; ++DY){
      if (dxx + DY*DY <= RAD*RAD){
        float sw = swrow[DY];               // wave-uniform load (no FP op)
        {
          const int B = BASE + 0 + DY;      // compile-time
          float shf = (float)((wrow[B >> 2] >> ((B & 3)*8)) & 255u);  // exact cvt
          float diff = asub(shf, c0);                                  // pinned sub
          int idx = (int)fabsf(diff);                                  // exact
          float w = amul(sw, wcr[(idx << 5) + lk]);                    // pinned mul
          afma(num0, w, shf);                                          // pinned FMA
          aacc(den0, w);                                               // pinned add
        }
        {
          const int B = BASE + 1 + DY;
          float shf = (float)((wrow[B >> 2] >> ((B & 3)*8)) & 255u);
          float diff = asub(shf, c1);
          int idx = (int)fabsf(diff);
          float w = amul(sw, wcr[(idx << 5) + lk]);
          afma(num1, w, shf);
          aacc(den1, w);
        }
      }
    }
  }
}

// ---------------- bilateral: 256 thr, 2 px/thread, 32x16 tile, 1024 blocks ----------------
// rr=tid>>3: row r=rr&15, ph=rr>>4 (wave-uniform). 4 blocks/CU x 4 waves = 16 waves/CU.
__global__ __launch_bounds__(256) void k_bilateral(const u8* __restrict__ q, u8* __restrict__ filt,
                                                   const float* __restrict__ wc_g,
                                                   const float* __restrict__ swt_g){
  __shared__ __align__(16) u8 sm[32768 + 46*68];
  float* wcr  = (float*)sm;                 // [256][32] replicated
  u8*   tileB = sm + 32768;                 // [46][68] halo tile (stride 68)
  int b = blockIdx.z;
  int gx0 = blockIdx.x * 32, gy0 = blockIdx.y * 16;
  int tid = threadIdx.x;
  const u8* qb = q + ((size_t)b << 16);
  {
    float v = wc_g[tid];
    float4 v4 = make_float4(v, v, v, v);
    #pragma unroll
    for (int k = 0; k < 8; ++k) *(float4*)&wcr[tid*32 + k*4] = v4;
  }
  for (int i = tid; i < 46*62; i += 256){
    int ly = i / 62, lx = i % 62;
    int gy = gy0 + ly - RAD, gx = gx0 + lx - RAD;
    gy = gy < 0 ? -gy : (gy > 255 ? 510 - gy : gy);   // jnp.pad reflect
    gx = gx < 0 ? -gx : (gx > 255 ? 510 - gx : gx);
    tileB[ly*68 + lx] = qb[(gy << 8) + gx];
  }
  __syncthreads();
  int tx8 = tid & 7, rr = tid >> 3;
  int r = rr & 15, ph = rr >> 4;            // ph wave-uniform
  int lk = tid & 31;
  int cbase = (r + RAD)*68 + RAD + 4*tx8 + 2*ph;
  float c0 = (float)tileB[cbase + 0];
  float c1 = (float)tileB[cbase + 1];
  float num0 = 0.f, den0 = 0.f, num1 = 0.f, den1 = 0.f;
  if (ph == 0) bil_body<15>(tileB, wcr, swt_g, r, tx8, lk, c0, c1, num0, den0, num1, den1);
  else         bil_body<17>(tileB, wcr, swt_g, r, tx8, lk, c0, c1, num0, den0, num1, den1);
  unsigned p0 = (unsigned)(int)rintf(__fdiv_rn(num0, den0));
  unsigned p1 = (unsigned)(int)rintf(__fdiv_rn(num1, den1));
  int gy = gy0 + r, gx = gx0 + 4*tx8 + 2*ph;
  *(ushort_t*)(filt + ((size_t)b << 16) + (gy << 8) + gx) = (ushort_t)(p0 | (p1 << 8));
}

// ---------------- per-block channel stats ----------------
template<int OC>
__device__ __forceinline__ void block_stats(const float* acc, float* red, int tid, float* out){
  #pragma unroll
  for (int c0 = 0; c0 < OC; c0 += 8){
    #pragma unroll
    for (int pass = 0; pass < 2; ++pass){
      __syncthreads();
      #pragma unroll
      for (int j = 0; j < 8; ++j){
        float v = acc[c0 + j];
        red[tid*8 + j] = pass ? __fmul_rn(v, v) : v;
      }
      __syncthreads();
      int i = tid >> 5, s = tid & 31;
      float v = 0.f;
      #pragma unroll
      for (int k = 0; k < 8; ++k) v += red[(s + 32*k)*8 + i];
      v += __shfl_xor(v, 1); v += __shfl_xor(v, 2); v += __shfl_xor(v, 4);
      v += __shfl_xor(v, 8); v += __shfl_xor(v, 16);
      if (s == 0) out[2*(c0 + i) + pass] = v;
    }
  }
}

// ---------------- fused LBP + conv1-stats: filt -> lbp (global) + part1 ----------------
__global__ __launch_bounds__(256) void k_lbp1(const u8* __restrict__ filt, const float* __restrict__ w1,
                                              u8* __restrict__ lbp, float* __restrict__ part1){
  __shared__ u8    ft[20][20];
  __shared__ float lt[18][18];
  __shared__ float wl[288];
  __shared__ float red[2048];
  int b = blockIdx.z;
  int ty0 = blockIdx.y * 16, tx0 = blockIdx.x * 16;
  int tid = threadIdx.x, tx = tid & 15, ty = tid >> 4;
  for (int i = tid; i < 288; i += 256) wl[i] = w1[i];
  for (int i = tid; i < 400; i += 256){
    int iy = i / 20, ix = i % 20;
    int gy = ty0 + iy - 2, gx = tx0 + ix - 2;
    u8 v = 0;
    if ((unsigned)gy < 256u && (unsigned)gx < 256u) v = filt[((size_t)b << 16) + (gy << 8) + gx];
    ft[iy][ix] = v;
  }
  __syncthreads();
  for (int i = tid; i < 324; i += 256){
    int jy = i / 18, jx = i % 18;
    int gy = ty0 + jy - 1, gx = tx0 + jx - 1;
    int pat = 0;
    if (gy > 0 && gy < 255 && gx > 0 && gx < 255){
      int c = ft[jy+1][jx+1];
      pat = 128;
      pat += (ft[jy+2][jx+1] >= c) ? 1  : 0;   // (+1, 0)
      pat += (ft[jy+1][jx  ] >= c) ? 6  : 0;   // ( 0,-1)
      pat += (ft[jy  ][jx  ] >= c) ? 8  : 0;   // (-1,-1)
      pat += (ft[jy  ][jx+1] >= c) ? 48 : 0;   // (-1, 0)
      pat += (ft[jy+1][jx+2] >= c) ? 64 : 0;   // ( 0,+1)
    }
    lt[jy][jx] = __fdiv_rn((float)pat, 255.0f);
    if (jy >= 1 && jy <= 16 && jx >= 1 && jx <= 16 && (unsigned)gy < 256u && (unsigned)gx < 256u)
      lbp[((size_t)b << 16) + (gy << 8) + gx] = (u8)pat;
  }
  __syncthreads();
  float v[9];
  #pragma unroll
  for (int j = 0; j < 9; ++j) v[j] = lt[ty + j/3][tx + j%3];
  float acc[32];
  #pragma unroll
  for (int oc = 0; oc < 32; ++oc){
    float a = 0.f;
    #pragma unroll
    for (int j = 0; j < 9; ++j) a = fmaf(v[j], wl[oc*9 + j], a);
    acc[oc] = a;
  }
  int blk = (blockIdx.z * 16 + blockIdx.y) * 16 + blockIdx.x;
  block_stats<32>(acc, red, tid, part1 + (size_t)blk * 64);
}

// ---------------- finalize BN stats ----------------
__global__ __launch_bounds__(256) void k_stats(const float* __restrict__ part, int stride, int OC,
                                               const float* __restrict__ g, const float* __restrict__ beta,
                                               float* __restrict__ st){
  int ch = blockIdx.x, tid = threadIdx.x;
  double s = 0.0, s2 = 0.0;
  for (int k = tid; k < 2048; k += 256){
    const float* pp = part + (size_t)k * stride + 2*ch;
    s += (double)pp[0]; s2 += (double)pp[1];
  }
  #pragma unroll
  for (int m = 1; m <= 32; m <<= 1){ s += __shfl_xor(s, m); s2 += __shfl_xor(s2, m); }
  __shared__ double red[8];
  if ((tid & 63) == 0){ red[(tid >> 6)*2] = s; red[(tid >> 6)*2 + 1] = s2; }
  __syncthreads();
  if (tid == 0){
    s  = red[0] + red[2] + red[4] + red[6];
    s2 = red[1] + red[3] + red[5] + red[7];
    double mean = s / 524288.0;
    double var  = s2 / 524288.0 - mean*mean;
    double rs   = 1.0 / sqrt(var + 1e-5);
    double sc   = (double)g[ch] * rs;
    st[ch]      = (float)sc;
    st[OC + ch] = (float)((double)beta[ch] - mean * sc);
  }
}

// ---------------- fused conv1+bn1+relu+conv2 (bf16 MFMA), stats2 + RAW pooled out ----------------
#define SM_Y1   0                       // ushort[324][40] = 25920 B
#define SM_LT   25920                   // float[400] = 1600 B
#define SM_WL   27520                   // float[288] = 1152 B
#define SM_RED  25920                   // float[512] alias (lt/wl dead post-conv1)
__global__ __launch_bounds__(256) void k_fused(const u8* __restrict__ lbp, const float* __restrict__ w1,
                                               const ushort_t* __restrict__ w2b,
                                               const float* __restrict__ st1,
                                               float* __restrict__ part2, float* __restrict__ out){
  __shared__ __align__(16) u8 smem[28672];
  ushort_t* y1h = (ushort_t*)(smem + SM_Y1);
  float*    lt  = (float*)(smem + SM_LT);
  float*    wl  = (float*)(smem + SM_WL);
  int b = blockIdx.z;
  int ty0 = blockIdx.y * 16, tx0 = blockIdx.x * 16;
  int tid = threadIdx.x;
  for (int i = tid; i < 288; i += 256) wl[i] = w1[i];
  for (int i = tid; i < 400; i += 256){
    int iy = i / 20, ix = i % 20;
    int gy = ty0 + iy - 2, gx = tx0 + ix - 2;
    float v = 0.f;
    if ((unsigned)gy < 256u && (unsigned)gx < 256u)
      v = __fdiv_rn((float)lbp[((size_t)b << 16) + (gy << 8) + gx], 255.0f);
    lt[i] = v;
  }
  __syncthreads();
  for (int i = tid; i < 324; i += 256){
    int jy = i / 18, jx = i % 18;
    int gy = ty0 + jy - 1, gx = tx0 + jx - 1;
    bool in = ((unsigned)gy < 256u) && ((unsigned)gx < 256u);
    float v[9];
    #pragma unroll
    for (int j = 0; j < 9; ++j) v[j] = lt[(jy + j/3)*20 + jx + j%3];
    ushort_t* row = y1h + i*40;
    #pragma unroll
    for (int o4 = 0; o4 < 4; ++o4){
      unsigned tmp[4];
      #pragma unroll
      for (int j2 = 0; j2 < 4; ++j2){
        int oc = o4*8 + j2*2;
        float a0 = 0.f, a1 = 0.f;
        #pragma unroll
        for (int j = 0; j < 9; ++j){
          a0 = fmaf(v[j], wl[(oc  )*9 + j], a0);
          a1 = fmaf(v[j], wl[(oc+1)*9 + j], a1);
        }
        float r0 = in ? fmaxf(fmaf(a0, st1[oc  ], st1[32 + oc  ]), 0.f) : 0.f;
        float r1 = in ? fmaxf(fmaf(a1, st1[oc+1], st1[32 + oc+1]), 0.f) : 0.f;
        tmp[j2] = (unsigned)f2bf(r0) | ((unsigned)f2bf(r1) << 16);
      }
      *(uint4*)(row + o4*8) = make_uint4(tmp[0], tmp[1], tmp[2], tmp[3]);
    }
  }
  __syncthreads();
  int lane = tid & 63, w = tid >> 6;
  int mA = lane & 15, g = lane >> 4;
  int pyA = mA >> 2, pxA = mA & 3;
  f32x4 acc[4][4] = {};
  #pragma unroll 3
  for (int t = 0; t < 9; ++t){
    int dy = t/3, dx = t%3;
    bf16x8 bf[4];
    #pragma unroll
    for (int o = 0; o < 4; ++o) bf[o] = *(const bf16x8*)(w2b + (((t*4 + o) << 6) + lane)*8);
    #pragma unroll
    for (int i = 0; i < 4; ++i){
      int jy = (w << 2) + pyA + dy, jx = (i << 2) + pxA + dx;
      bf16x8 a = *(const bf16x8*)(y1h + (jy*18 + jx)*40 + g*8);
      #pragma unroll
      for (int o = 0; o < 4; ++o)
        acc[i][o] = __builtin_amdgcn_mfma_f32_16x16x32_bf16(a, bf[o], acc[i][o], 0, 0, 0);
    }
  }
  int col = lane & 15;
  // ---- stats2 partials ----
  {
    float* red = (float*)(smem + SM_RED);
    float s[4], s2[4];
    #pragma unroll
    for (int o = 0; o < 4; ++o){
      s[o] = 0.f; s2[o] = 0.f;
      #pragma unroll
      for (int i = 0; i < 4; ++i)
        #pragma unroll
        for (int rr = 0; rr < 4; ++rr){
          float v = acc[i][o][rr];
          s[o] += v; s2[o] = fmaf(v, v, s2[o]);
        }
      s[o]  += __shfl_xor(s[o], 16);  s[o]  += __shfl_xor(s[o], 32);
      s2[o] += __shfl_xor(s2[o], 16); s2[o] += __shfl_xor(s2[o], 32);
    }
    if (g == 0){
      #pragma unroll
      for (int o = 0; o < 4; ++o){
        red[((0*4 + w)*4 + o)*16 + col] = s[o];
        red[((1*4 + w)*4 + o)*16 + col] = s2[o];
      }
    }
    __syncthreads();
    if (tid < 128){
      int stat = tid >> 6, oc = tid & 63, o = oc >> 4, c = oc & 15;
      float* red2 = (float*)(smem + SM_RED);
      float sum = 0.f;
      #pragma unroll
      for (int ww = 0; ww < 4; ++ww) sum += red2[((stat*4 + ww)*4 + o)*16 + c];
      int blk = (blockIdx.z * 16 + blockIdx.y) * 16 + blockIdx.x;
      part2[(size_t)blk * 128 + 2*oc + stat] = sum;
    }
  }
  // ---- raw 2x2 maxpool -> out ----
  {
    float* pool = (float*)(smem + SM_Y1);
    #pragma unroll
    for (int o = 0; o < 4; ++o){
      int oc = (o << 4) + col;
      #pragma unroll
      for (int i = 0; i < 4; ++i){
        float h0 = fmaxf(acc[i][o][0], acc[i][o][1]);
        float h2 = fmaxf(acc[i][o][2], acc[i][o][3]);
        float p0 = fmaxf(h0, __shfl_xor(h0, 16));
        float p2 = fmaxf(h2, __shfl_xor(h2, 16));
        if (!(g & 1)){
          *(float2*)&pool[oc*66 + (w*2 + (g >> 1))*8 + i*2] = make_float2(p0, p2);
        }
      }
    }
    __syncthreads();
    int Y0 = blockIdx.y * 8, X0 = blockIdx.x * 8;
    for (int k = tid; k < 1024; k += 256){
      int oc = k >> 4, quad = k & 15;
      int row = quad >> 1, c4 = (quad & 1) * 4;
      float4 v = *(float4*)&pool[oc*66 + quad*4];
      *(float4*)&out[(((size_t)b*64 + oc) << 14) + (size_t)(Y0 + row)*128 + X0 + c4] = v;
    }
  }
}

// ---------------- bn2 + relu, in-place on pooled out ----------------
__global__ __launch_bounds__(256) void k_bn2(float* __restrict__ out, const float* __restrict__ st2){
  int i = blockIdx.x*256 + threadIdx.x;       // 2097152 float4
  int oc = (i >> 12) & 63;
  float sc = st2[oc], sh = st2[64 + oc];
  float4 v = ((float4*)out)[i];
  v.x = fmaxf(fmaf(v.x, sc, sh), 0.f);
  v.y = fmaxf(fmaf(v.y, sc, sh), 0.f);
  v.z = fmaxf(fmaf(v.z, sc, sh), 0.f);
  v.w = fmaxf(fmaf(v.w, sc, sh), 0.f);
  ((float4*)out)[i] = v;
}

extern "C" void kernel_launch(void* const* d_in, const int* in_sizes, int n_in,
                              void* d_out, int out_size, void* d_ws, size_t ws_size,
                              hipStream_t stream){
  const float* img = (const float*)d_in[0];
  const float* w1  = (const float*)d_in[1];
  const float* g1  = (const float*)d_in[3];
  const float* be1 = (const float*)d_in[4];
  const float* w2  = (const float*)d_in[5];
  const float* g2  = (const float*)d_in[7];
  const float* be2 = (const float*)d_in[8];
  float* out = (float*)d_out;

  char* base = (char*)d_ws;                       // ~3.2 MB total
  u8*       q    = (u8*)(base + 0);
  u8*       filt = (u8*)(base + 524288);
  u8*       lbp  = (u8*)(base + 1048576);
  ushort_t* w2b  = (ushort_t*)(base + 1572864);   // 36864
  float*    wc_g = (float*)(base + 1609728);      // 1024
  float*    swtg = (float*)(base + 1610752);      // 3856
  float*    p1   = (float*)(base + 1614608);      // 524288
  float*    p2   = (float*)(base + 2138896);      // 1048576
  float*    st1  = (float*)(base + 3187472);      // 256
  float*    st2  = (float*)(base + 3187728);      // 512

  k_gp       <<<2121, 256, 0, stream>>>(img, q, w2, w2b, wc_g, swtg);
  k_bilateral<<<dim3(8,16,8), 256, 0, stream>>>(q, filt, wc_g, swtg);
  k_lbp1     <<<dim3(16,16,8), 256, 0, stream>>>(filt, w1, lbp, p1);
  k_stats    <<<32, 256, 0, stream>>>(p1, 64, 32, g1, be1, st1);
  k_fused    <<<dim3(16,16,8), 256, 0, stream>>>(lbp, w1, w2b, st1, p2, out);
  k_stats    <<<64, 256, 0, stream>>>(p2, 128, 64, g2, be2, st2);
  k_bn2      <<<8192, 256, 0, stream>>>(out, st2);
}

// Round 19
// 195.688 us; speedup vs baseline: 7.0403x; 1.0048x over previous
//
#include <hip/hip_runtime.h>
#include <math.h>

#define RAD 15
#define DIAM 31

typedef unsigned char u8;
typedef unsigned short ushort_t;
typedef __attribute__((ext_vector_type(8))) short bf16x8;
typedef __attribute__((ext_vector_type(4))) float f32x4;

__device__ __forceinline__ unsigned short f2bf(float f){
  unsigned u = __float_as_uint(f);
  return (unsigned short)((u + 0x7FFFu + ((u >> 16) & 1u)) >> 16);
}

// asm-pinned IEEE fp32 ops: compiler cannot contract/reassociate/resequence these.
__device__ __forceinline__ float asub(float a, float b){ float d; asm("v_sub_f32 %0, %1, %2" : "=v"(d) : "v"(a), "v"(b)); return d; }
__device__ __forceinline__ float amul(float a, float b){ float d; asm("v_mul_f32 %0, %1, %2" : "=v"(d) : "v"(a), "v"(b)); return d; }
__device__ __forceinline__ void  aacc(float& acc, float v){ asm("v_add_f32 %0, %0, %1" : "+v"(acc) : "v"(v)); }
// fused num-accumulate: the np/XLA reference evaluates num + w*sh as FMA (verified R17).
__device__ __forceinline__ void  afma(float& acc, float a, float b){ asm("v_fmac_f32 %0, %1, %2" : "+v"(acc) : "v"(a), "v"(b)); }

// ---------------- merged: gray+quantize | w2 frags | exp tables ----------------
__global__ __launch_bounds__(256) void k_gp(const float* __restrict__ img, u8* __restrict__ q,
                                            const float* __restrict__ w2, ushort_t* __restrict__ w2b,
                                            float* __restrict__ wc_g, float* __restrict__ swt_g){
  int blk = blockIdx.x, tid = threadIdx.x;
  if (blk < 2048){
    int i = blk*256 + tid;
    int b = i >> 16, p = i & 65535;
    const float* pb = img + (((size_t)b*3) << 16);
    float r = pb[p], g = pb[65536 + p], bl = pb[131072 + p];
    float gray = __fadd_rn(__fadd_rn(__fmul_rn(0.299f, r), __fmul_rn(0.587f, g)), __fmul_rn(0.116f, bl));
    float t = floorf(__fmul_rn(gray, 255.0f));
    t = fminf(fmaxf(t, 0.0f), 255.0f);
    q[i] = (u8)(int)t;
  } else if (blk < 2120){
    int i = (blk - 2048)*256 + tid;     // 72*256 = 18432
    int j = i & 7, l = (i >> 3) & 63, fo = i >> 9;
    int t = fo >> 2, o = fo & 3;
    int oc = o*16 + (l & 15), ic = (l >> 4)*8 + j;
    w2b[i] = f2bf(w2[(oc*32 + ic)*9 + t]);
  } else {
    const float inv2sc2 = (float)(-0.5/5625.0);
    float df = (float)tid;
    float t = __fmul_rn(__fmul_rn(inv2sc2, df), df);
    wc_g[tid] = (float)exp((double)t);                 // correctly-rounded f32 exp
    for (int i = tid; i < DIAM*DIAM; i += 256){
      int dx = i / DIAM - RAD, dy = i % DIAM - RAD;
      int r2 = dx*dx + dy*dy;
      swt_g[i] = (r2 <= RAD*RAD) ? (float)exp(-0.5 * (double)r2 / 225.0) : 0.0f;
    }
  }
}

// ---------------- bilateral per-pixel-pair body (pinned FMA chain, verified R17) ----------------
template<int BASE>
__device__ __forceinline__ void bil_body(const u8* tileB, const float* wcr, const float* swt_g,
                                         int r, int tx8, int lk, float c0, float c1,
                                         float& num0, float& den0, float& num1, float& den1){
  #pragma unroll 1
  for (int dx = -RAD; dx <= RAD; ++dx){
    int dxx = dx*dx;
    int rowoff = (r + dx + RAD)*68 + 4*tx8;
    unsigned wrow[9];
    #pragma unroll
    for (int k = 0; k < 9; ++k) wrow[k] = *(const unsigned*)(tileB + rowoff + 4*k);
    const float* swrow = swt_g + (dx + RAD)*DIAM + RAD;
    #pragma unroll
    for (int DY = -RAD; DY <= RAD; ++DY){
      if (dxx + DY*DY <= RAD*RAD){
        float sw = swrow[DY];               // wave-uniform load (no FP op)
        {
          const int B = BASE + 0 + DY;      // compile-time after unroll
          float shf = (float)((wrow[B >> 2] >> ((B & 3)*8)) & 255u);  // exact cvt
          float diff = asub(shf, c0);               // pinned sub
          int idx = (int)fabsf(diff);               // exact
          float w = amul(sw, wcr[(idx << 4) + lk]); // pinned mul, 16-way repl gather
          afma(num0, w, shf);                       // pinned FMA (matches ref)
          aacc(den0, w);                            // pinned add
        }
        {
          const int B = BASE + 1 + DY;
          float shf = (float)((wrow[B >> 2] >> ((B & 3)*8)) & 255u);
          float diff = asub(shf, c1);
          int idx = (int)fabsf(diff);
          float w = amul(sw, wcr[(idx << 4) + lk]);
          afma(num1, w, shf);
          aacc(den1, w);
        }
      }
    }
  }
}

// ---------------- bilateral: 256 thr, 2 px/thread, 16-way wcr, 8 blocks/CU ----------------
// LDS 19.5KB -> 8 blocks x 4 waves = 32 waves/CU (2x R17). Gather lanes {L,L+16,L+32,L+48}
// share lk -> <=2 distinct banks per quartet -> mostly 2-way (free), worst 4-way.
__global__ __launch_bounds__(256) void k_bilateral(const u8* __restrict__ q, u8* __restrict__ filt,
                                                   const float* __restrict__ wc_g,
                                                   const float* __restrict__ swt_g){
  __shared__ __align__(16) u8 sm[16384 + 46*68];
  float* wcr  = (float*)sm;                 // [256][16] replicated
  u8*   tileB = sm + 16384;                 // [46][68] halo tile (stride 68)
  int b = blockIdx.z;
  int gx0 = blockIdx.x * 32, gy0 = blockIdx.y * 16;
  int tid = threadIdx.x;
  const u8* qb = q + ((size_t)b << 16);
  {
    float v = wc_g[tid];
    float4 v4 = make_float4(v, v, v, v);
    #pragma unroll
    for (int k = 0; k < 4; ++k) *(float4*)&wcr[tid*16 + k*4] = v4;
  }
  for (int i = tid; i < 46*62; i += 256){
    int ly = i / 62, lx = i % 62;
    int gy = gy0 + ly - RAD, gx = gx0 + lx - RAD;
    gy = gy < 0 ? -gy : (gy > 255 ? 510 - gy : gy);   // jnp.pad reflect
    gx = gx < 0 ? -gx : (gx > 255 ? 510 - gx : gx);
    tileB[ly*68 + lx] = qb[(gy << 8) + gx];
  }
  __syncthreads();
  int tx8 = tid & 7, rr = tid >> 3;
  int r = rr & 15, ph = rr >> 4;            // ph wave-uniform
  int lk = tid & 15;
  int cbase = (r + RAD)*68 + RAD + 4*tx8 + 2*ph;
  float c0 = (float)tileB[cbase + 0];
  float c1 = (float)tileB[cbase + 1];
  float num0 = 0.f, den0 = 0.f, num1 = 0.f, den1 = 0.f;
  if (ph == 0) bil_body<15>(tileB, wcr, swt_g, r, tx8, lk, c0, c1, num0, den0, num1, den1);
  else         bil_body<17>(tileB, wcr, swt_g, r, tx8, lk, c0, c1, num0, den0, num1, den1);
  unsigned p0 = (unsigned)(int)rintf(__fdiv_rn(num0, den0));
  unsigned p1 = (unsigned)(int)rintf(__fdiv_rn(num1, den1));
  int gy = gy0 + r, gx = gx0 + 4*tx8 + 2*ph;
  *(ushort_t*)(filt + ((size_t)b << 16) + (gy << 8) + gx) = (ushort_t)(p0 | (p1 << 8));
}

// ---------------- per-block channel stats ----------------
template<int OC>
__device__ __forceinline__ void block_stats(const float* acc, float* red, int tid, float* out){
  #pragma unroll
  for (int c0 = 0; c0 < OC; c0 += 8){
    #pragma unroll
    for (int pass = 0; pass < 2; ++pass){
      __syncthreads();
      #pragma unroll
      for (int j = 0; j < 8; ++j){
        float v = acc[c0 + j];
        red[tid*8 + j] = pass ? __fmul_rn(v, v) : v;
      }
      __syncthreads();
      int i = tid >> 5, s = tid & 31;
      float v = 0.f;
      #pragma unroll
      for (int k = 0; k < 8; ++k) v += red[(s + 32*k)*8 + i];
      v += __shfl_xor(v, 1); v += __shfl_xor(v, 2); v += __shfl_xor(v, 4);
      v += __shfl_xor(v, 8); v += __shfl_xor(v, 16);
      if (s == 0) out[2*(c0 + i) + pass] = v;
    }
  }
}

// ---------------- fused LBP + conv1-stats: filt -> lbp (global) + part1 ----------------
__global__ __launch_bounds__(256) void k_lbp1(const u8* __restrict__ filt, const float* __restrict__ w1,
                                              u8* __restrict__ lbp, float* __restrict__ part1){
  __shared__ u8    ft[20][20];
  __shared__ float lt[18][18];
  __shared__ float wl[288];
  __shared__ float red[2048];
  int b = blockIdx.z;
  int ty0 = blockIdx.y * 16, tx0 = blockIdx.x * 16;
  int tid = threadIdx.x, tx = tid & 15, ty = tid >> 4;
  for (int i = tid; i < 288; i += 256) wl[i] = w1[i];
  for (int i = tid; i < 400; i += 256){
    int iy = i / 20, ix = i % 20;
    int gy = ty0 + iy - 2, gx = tx0 + ix - 2;
    u8 v = 0;
    if ((unsigned)gy < 256u && (unsigned)gx < 256u) v = filt[((size_t)b << 16) + (gy << 8) + gx];
    ft[iy][ix] = v;
  }
  __syncthreads();
  for (int i = tid; i < 324; i += 256){
    int jy = i / 18, jx = i % 18;
    int gy = ty0 + jy - 1, gx = tx0 + jx - 1;
    int pat = 0;
    if (gy > 0 && gy < 255 && gx > 0 && gx < 255){
      int c = ft[jy+1][jx+1];
      pat = 128;
      pat += (ft[jy+2][jx+1] >= c) ? 1  : 0;   // (+1, 0)
      pat += (ft[jy+1][jx  ] >= c) ? 6  : 0;   // ( 0,-1)
      pat += (ft[jy  ][jx  ] >= c) ? 8  : 0;   // (-1,-1)
      pat += (ft[jy  ][jx+1] >= c) ? 48 : 0;   // (-1, 0)
      pat += (ft[jy+1][jx+2] >= c) ? 64 : 0;   // ( 0,+1)
    }
    lt[jy][jx] = __fdiv_rn((float)pat, 255.0f);
    if (jy >= 1 && jy <= 16 && jx >= 1 && jx <= 16 && (unsigned)gy < 256u && (unsigned)gx < 256u)
      lbp[((size_t)b << 16) + (gy << 8) + gx] = (u8)pat;
  }
  __syncthreads();
  float v[9];
  #pragma unroll
  for (int j = 0; j < 9; ++j) v[j] = lt[ty + j/3][tx + j%3];
  float acc[32];
  #pragma unroll
  for (int oc = 0; oc < 32; ++oc){
    float a = 0.f;
    #pragma unroll
    for (int j = 0; j < 9; ++j) a = fmaf(v[j], wl[oc*9 + j], a);
    acc[oc] = a;
  }
  int blk = (blockIdx.z * 16 + blockIdx.y) * 16 + blockIdx.x;
  block_stats<32>(acc, red, tid, part1 + (size_t)blk * 64);
}

// ---------------- finalize BN stats ----------------
__global__ __launch_bounds__(256) void k_stats(const float* __restrict__ part, int stride, int OC,
                                               const float* __restrict__ g, const float* __restrict__ beta,
                                               float* __restrict__ st){
  int ch = blockIdx.x, tid = threadIdx.x;
  double s = 0.0, s2 = 0.0;
  for (int k = tid; k < 2048; k += 256){
    const float* pp = part + (size_t)k * stride + 2*ch;
    s += (double)pp[0]; s2 += (double)pp[1];
  }
  #pragma unroll
  for (int m = 1; m <= 32; m <<= 1){ s += __shfl_xor(s, m); s2 += __shfl_xor(s2, m); }
  __shared__ double red[8];
  if ((tid & 63) == 0){ red[(tid >> 6)*2] = s; red[(tid >> 6)*2 + 1] = s2; }
  __syncthreads();
  if (tid == 0){
    s  = red[0] + red[2] + red[4] + red[6];
    s2 = red[1] + red[3] + red[5] + red[7];
    double mean = s / 524288.0;
    double var  = s2 / 524288.0 - mean*mean;
    double rs   = 1.0 / sqrt(var + 1e-5);
    double sc   = (double)g[ch] * rs;
    st[ch]      = (float)sc;
    st[OC + ch] = (float)((double)beta[ch] - mean * sc);
  }
}

// ---------------- fused conv1+bn1+relu+conv2 (bf16 MFMA), stats2 + RAW pooled out ----------------
#define SM_Y1   0                       // ushort[324][40] = 25920 B
#define SM_LT   25920                   // float[400] = 1600 B
#define SM_WL   27520                   // float[288] = 1152 B
#define SM_RED  25920                   // float[512] alias (lt/wl dead post-conv1)
__global__ __launch_bounds__(256) void k_fused(const u8* __restrict__ lbp, const float* __restrict__ w1,
                                               const ushort_t* __restrict__ w2b,
                                               const float* __restrict__ st1,
                                               float* __restrict__ part2, float* __restrict__ out){
  __shared__ __align__(16) u8 smem[28672];
  ushort_t* y1h = (ushort_t*)(smem + SM_Y1);
  float*    lt  = (float*)(smem + SM_LT);
  float*    wl  = (float*)(smem + SM_WL);
  int b = blockIdx.z;
  int ty0 = blockIdx.y * 16, tx0 = blockIdx.x * 16;
  int tid = threadIdx.x;
  for (int i = tid; i < 288; i += 256) wl[i] = w1[i];
  for (int i = tid; i < 400; i += 256){
    int iy = i / 20, ix = i % 20;
    int gy = ty0 + iy - 2, gx = tx0 + ix - 2;
    float v = 0.f;
    if ((unsigned)gy < 256u && (unsigned)gx < 256u)
      v = __fdiv_rn((float)lbp[((size_t)b << 16) + (gy << 8) + gx], 255.0f);
    lt[i] = v;
  }
  __syncthreads();
  for (int i = tid; i < 324; i += 256){
    int jy = i / 18, jx = i % 18;
    int gy = ty0 + jy - 1, gx = tx0 + jx - 1;
    bool in = ((unsigned)gy < 256u) && ((unsigned)gx < 256u);
    float v[9];
    #pragma unroll
    for (int j = 0; j < 9; ++j) v[j] = lt[(jy + j/3)*20 + jx + j%3];
    ushort_t* row = y1h + i*40;
    #pragma unroll
    for (int o4 = 0; o4 < 4; ++o4){
      unsigned tmp[4];
      #pragma unroll
      for (int j2 = 0; j2 < 4; ++j2){
        int oc = o4*8 + j2*2;
        float a0 = 0.f, a1 = 0.f;
        #pragma unroll
        for (int j = 0; j < 9; ++j){
          a0 = fmaf(v[j], wl[(oc  )*9 + j], a0);
          a1 = fmaf(v[j], wl[(oc+1)*9 + j], a1);
        }
        float r0 = in ? fmaxf(fmaf(a0, st1[oc  ], st1[32 + oc  ]), 0.f) : 0.f;
        float r1 = in ? fmaxf(fmaf(a1, st1[oc+1], st1[32 + oc+1]), 0.f) : 0.f;
        tmp[j2] = (unsigned)f2bf(r0) | ((unsigned)f2bf(r1) << 16);
      }
      *(uint4*)(row + o4*8) = make_uint4(tmp[0], tmp[1], tmp[2], tmp[3]);
    }
  }
  __syncthreads();
  int lane = tid & 63, w = tid >> 6;
  int mA = lane & 15, g = lane >> 4;
  int pyA = mA >> 2, pxA = mA & 3;
  f32x4 acc[4][4] = {};
  #pragma unroll 3
  for (int t = 0; t < 9; ++t){
    int dy = t/3, dx = t%3;
    bf16x8 bf[4];
    #pragma unroll
    for (int o = 0; o < 4; ++o) bf[o] = *(const bf16x8*)(w2b + (((t*4 + o) << 6) + lane)*8);
    #pragma unroll
    for (int i = 0; i < 4; ++i){
      int jy = (w << 2) + pyA + dy, jx = (i << 2) + pxA + dx;
      bf16x8 a = *(const bf16x8*)(y1h + (jy*18 + jx)*40 + g*8);
      #pragma unroll
      for (int o = 0; o < 4; ++o)
        acc[i][o] = __builtin_amdgcn_mfma_f32_16x16x32_bf16(a, bf[o], acc[i][o], 0, 0, 0);
    }
  }
  int col = lane & 15;
  // ---- stats2 partials ----
  {
    float* red = (float*)(smem + SM_RED);
    float s[4], s2[4];
    #pragma unroll
    for (int o = 0; o < 4; ++o){
      s[o] = 0.f; s2[o] = 0.f;
      #pragma unroll
      for (int i = 0; i < 4; ++i)
        #pragma unroll
        for (int rr = 0; rr < 4; ++rr){
          float v = acc[i][o][rr];
          s[o] += v; s2[o] = fmaf(v, v, s2[o]);
        }
      s[o]  += __shfl_xor(s[o], 16);  s[o]  += __shfl_xor(s[o], 32);
      s2[o] += __shfl_xor(s2[o], 16); s2[o] += __shfl_xor(s2[o], 32);
    }
    if (g == 0){
      #pragma unroll
      for (int o = 0; o < 4; ++o){
        red[((0*4 + w)*4 + o)*16 + col] = s[o];
        red[((1*4 + w)*4 + o)*16 + col] = s2[o];
      }
    }
    __syncthreads();
    if (tid < 128){
      int stat = tid >> 6, oc = tid & 63, o = oc >> 4, c = oc & 15;
      float* red2 = (float*)(smem + SM_RED);
      float sum = 0.f;
      #pragma unroll
      for (int ww = 0; ww < 4; ++ww) sum += red2[((stat*4 + ww)*4 + o)*16 + c];
      int blk = (blockIdx.z * 16 + blockIdx.y) * 16 + blockIdx.x;
      part2[(size_t)blk * 128 + 2*oc + stat] = sum;
    }
  }
  // ---- raw 2x2 maxpool -> out ----
  {
    float* pool = (float*)(smem + SM_Y1);
    #pragma unroll
    for (int o = 0; o < 4; ++o){
      int oc = (o << 4) + col;
      #pragma unroll
      for (int i = 0; i < 4; ++i){
        float h0 = fmaxf(acc[i][o][0], acc[i][o][1]);
        float h2 = fmaxf(acc[i][o][2], acc[i][o][3]);
        float p0 = fmaxf(h0, __shfl_xor(h0, 16));
        float p2 = fmaxf(h2, __shfl_xor(h2, 16));
        if (!(g & 1)){
          *(float2*)&pool[oc*66 + (w*2 + (g >> 1))*8 + i*2] = make_float2(p0, p2);
        }
      }
    }
    __syncthreads();
    int Y0 = blockIdx.y * 8, X0 = blockIdx.x * 8;
    for (int k = tid; k < 1024; k += 256){
      int oc = k >> 4, quad = k & 15;
      int row = quad >> 1, c4 = (quad & 1) * 4;
      float4 v = *(float4*)&pool[oc*66 + quad*4];
      *(float4*)&out[(((size_t)b*64 + oc) << 14) + (size_t)(Y0 + row)*128 + X0 + c4] = v;
    }
  }
}

// ---------------- bn2 + relu, in-place on pooled out ----------------
__global__ __launch_bounds__(256) void k_bn2(float* __restrict__ out, const float* __restrict__ st2){
  int i = blockIdx.x*256 + threadIdx.x;       // 2097152 float4
  int oc = (i >> 12) & 63;
  float sc = st2[oc], sh = st2[64 + oc];
  float4 v = ((float4*)out)[i];
  v.x = fmaxf(fmaf(v.x, sc, sh), 0.f);
  v.y = fmaxf(fmaf(v.y, sc, sh), 0.f);
  v.z = fmaxf(fmaf(v.z, sc, sh), 0.f);
  v.w = fmaxf(fmaf(v.w, sc, sh), 0.f);
  ((float4*)out)[i] = v;
}

extern "C" void kernel_launch(void* const* d_in, const int* in_sizes, int n_in,
                              void* d_out, int out_size, void* d_ws, size_t ws_size,
                              hipStream_t stream){
  const float* img = (const float*)d_in[0];
  const float* w1  = (const float*)d_in[1];
  const float* g1  = (const float*)d_in[3];
  const float* be1 = (const float*)d_in[4];
  const float* w2  = (const float*)d_in[5];
  const float* g2  = (const float*)d_in[7];
  const float* be2 = (const float*)d_in[8];
  float* out = (float*)d_out;

  char* base = (char*)d_ws;                       // ~3.2 MB total
  u8*       q    = (u8*)(base + 0);
  u8*       filt = (u8*)(base + 524288);
  u8*       lbp  = (u8*)(base + 1048576);
  ushort_t* w2b  = (ushort_t*)(base + 1572864);   // 36864
  float*    wc_g = (float*)(base + 1609728);      // 1024
  float*    swtg = (float*)(base + 1610752);      // 3856
  float*    p1   = (float*)(base + 1614608);      // 524288
  float*    p2   = (float*)(base + 2138896);      // 1048576
  float*    st1  = (float*)(base + 3187472);      // 256
  float*    st2  = (float*)(base + 3187728);      // 512

  k_gp       <<<2121, 256, 0, stream>>>(img, q, w2, w2b, wc_g, swtg);
  k_bilateral<<<dim3(8,16,8), 256, 0, stream>>>(q, filt, wc_g, swtg);
  k_lbp1     <<<dim3(16,16,8), 256, 0, stream>>>(filt, w1, lbp, p1);
  k_stats    <<<32, 256, 0, stream>>>(p1, 64, 32, g1, be1, st1);
  k_fused    <<<dim3(16,16,8), 256, 0, stream>>>(lbp, w1, w2b, st1, p2, out);
  k_stats    <<<64, 256, 0, stream>>>(p2, 128, 64, g2, be2, st2);
  k_bn2      <<<8192, 256, 0, stream>>>(out, st2);
}